// Round 1
// baseline (3415.143 us; speedup 1.0000x reference)
//
#include <hip/hip_runtime.h>

#define B_      2
#define NO_     96
#define T_      50
#define SD_     4
#define NE_     (NO_*(NO_-1))   /* 9120 */
#define F_      64
#define L_      64
#define K_      8
#define NW_     15
#define TSTR    56              /* padded time stride: [0,1]=left pad, data at +2, [52,53]=right pad */

/* ---- workspace layout (floats) ---- */
#define SZ_W0T    (24*64)
#define SZ_CT     (2*320*64)
#define SZ_FC1T   (512*64)
#define SZ_FC2T   (64*64)
#define SZ_RBL    (2*64*128)
#define SZ_MLL    (3*64*128)
#define SZ_MLF    (3*64*64)

#define OFF_W0T   0
#define OFF_C1T   (OFF_W0T  + SZ_W0T)
#define OFF_C2T   (OFF_C1T  + SZ_CT)
#define OFF_FC1T  (OFF_C2T  + SZ_CT)
#define OFF_FC2T  (OFF_FC1T + SZ_FC1T)
#define OFF_RBL1  (OFF_FC2T + SZ_FC2T)
#define OFF_RBL2  (OFF_RBL1 + SZ_RBL)
#define OFF_MLL1  (OFF_RBL2 + SZ_RBL)
#define OFF_MLL2  (OFF_MLL1 + SZ_MLL)
#define OFF_MLF1  (OFF_MLL2 + SZ_MLL)
#define OFF_MLF2  (OFF_MLF1 + SZ_MLF)
#define WS_TOTAL  (OFF_MLF2 + SZ_MLF)

__device__ __forceinline__ float swish_(float v) {
    return v / (1.f + __expf(-v));
}

/* Transpose all weights so that the fastest-varying index is the OUTPUT channel
   (lane id) -> coalesced 256B wave loads inside the main kernel. */
__global__ void prep_kernel(const float* __restrict__ cnnbf_w,
                            const float* __restrict__ rb1w, const float* __restrict__ rb2w,
                            const float* __restrict__ fc1w, const float* __restrict__ fc2w,
                            const float* __restrict__ rbl1w, const float* __restrict__ rbl2w,
                            const float* __restrict__ mll1w, const float* __restrict__ mll2w,
                            const float* __restrict__ mlf1w, const float* __restrict__ mlf2w,
                            float* __restrict__ ws) {
    int idx = blockIdx.x * blockDim.x + threadIdx.x;
    if (idx >= WS_TOTAL) return;
    int r = idx;
    float v;
    if (r < SZ_W0T) {                       /* w0t[(fi*3+k)*64+fo] <- cnnbf_w[fo][fi][k], fi<8,k<3 */
        int fo = r & 63, q = r >> 6, fi = q / 3, k = q % 3;
        v = cnnbf_w[(fo*8 + fi)*3 + k];
    } else if ((r -= SZ_W0T) < SZ_CT) {     /* c1t[i][(fi*5+k)*64+fo] <- rb_conv1_w[i][fo][fi][k] */
        int i = r / (320*64), s = r % (320*64);
        int fo = s & 63, q = s >> 6, fi = q / 5, k = q % 5;
        v = rb1w[((i*64 + fo)*64 + fi)*5 + k];
    } else if ((r -= SZ_CT) < SZ_CT) {      /* c2t */
        int i = r / (320*64), s = r % (320*64);
        int fo = s & 63, q = s >> 6, fi = q / 5, k = q % 5;
        v = rb2w[((i*64 + fo)*64 + fi)*5 + k];
    } else if ((r -= SZ_CT) < SZ_FC1T) {    /* fc1t[j*64+fo] <- mlp1_fc1_w[fo][j], j<512 */
        int fo = r & 63, j = r >> 6;
        v = fc1w[fo*512 + j];
    } else if ((r -= SZ_FC1T) < SZ_FC2T) {  /* fc2t[fi*64+fo] <- mlp1_fc2_w[fo][fi] */
        int fo = r & 63, fi = r >> 6;
        v = fc2w[fo*64 + fi];
    } else if ((r -= SZ_FC2T) < SZ_RBL) {   /* rbl1t[i][j*128+o] <- rb_lfc1_w[i][o][j] */
        int i = r / (64*128), s = r % (64*128);
        int o = s & 127, j = s >> 7;
        v = rbl1w[(i*128 + o)*64 + j];
    } else if ((r -= SZ_RBL) < SZ_RBL) {    /* rbl2t */
        int i = r / (64*128), s = r % (64*128);
        int o = s & 127, j = s >> 7;
        v = rbl2w[(i*128 + o)*64 + j];
    } else if ((r -= SZ_RBL) < SZ_MLL) {    /* mll1t[i][j*128+o] <- ml_lfc1_w[i][o][j] */
        int i = r / (64*128), s = r % (64*128);
        int o = s & 127, j = s >> 7;
        v = mll1w[(i*128 + o)*64 + j];
    } else if ((r -= SZ_MLL) < SZ_MLL) {    /* mll2t */
        int i = r / (64*128), s = r % (64*128);
        int o = s & 127, j = s >> 7;
        v = mll2w[(i*128 + o)*64 + j];
    } else if ((r -= SZ_MLL) < SZ_MLF) {    /* mlf1t[i][j*64+o] <- ml_fc1_w[i][o][j] */
        int i = r / (64*64), s = r % (64*64);
        int o = s & 63, j = s >> 6;
        v = mlf1w[(i*64 + o)*64 + j];
    } else {                                /* mlf2t */
        r -= SZ_MLF;
        int i = r / (64*64), s = r % (64*64);
        int o = s & 63, j = s >> 6;
        v = mlf2w[(i*64 + o)*64 + j];
    }
    ws[idx] = v;
}

/* conv 64ch -> 64ch, k=5, pad=2, with per-channel gate/shift + swish epilogue.
   lane = output channel, wave = 13-wide t-chunk. ACC: dst += result (residual). */
template <bool ACC>
__device__ __forceinline__ void conv5_block(const float (&src)[F_][TSTR],
                                            float (&dst)[F_][TSTR],
                                            const float* __restrict__ wt,   /* [320][64] */
                                            const float* __restrict__ cb,   /* [64] conv bias */
                                            float g, float bsh,
                                            int lane, int wv) {
    const int t0 = wv * 13;
    float acc[13];
    const float bias = cb[lane];
#pragma unroll
    for (int j = 0; j < 13; ++j) acc[j] = bias;
    for (int fi = 0; fi < 64; ++fi) {
        float xr[17];
#pragma unroll
        for (int m = 0; m < 17; ++m) xr[m] = src[fi][t0 + m];   /* broadcast reads */
        const float* wrow = wt + fi * 5 * 64 + lane;
#pragma unroll
        for (int k = 0; k < 5; ++k) {
            const float w = wrow[k * 64];
#pragma unroll
            for (int j = 0; j < 13; ++j) acc[j] += w * xr[j + k];
        }
    }
#pragma unroll
    for (int j = 0; j < 13; ++j) {
        const int t = t0 + j;
        if (t < T_) {
            const float v = g * acc[j] + bsh;
            const float s = swish_(v);
            if (ACC) dst[lane][t + 2] += s;
            else     dst[lane][t + 2] = s;
        }
    }
}

__global__ __launch_bounds__(256) void mega_kernel(
    const float* __restrict__ states, const float* __restrict__ latent,
    const float* __restrict__ cnnbf_b,
    const float* __restrict__ rb_conv1_b, const float* __restrict__ rb_conv2_b,
    const float* __restrict__ rb_lfc1_b, const float* __restrict__ rb_lfc2_b,
    const float* __restrict__ mlp1_fc1_b, const float* __restrict__ mlp1_fc2_b,
    const float* __restrict__ ml_fc1_b, const float* __restrict__ ml_fc2_b,
    const float* __restrict__ ml_lfc1_b, const float* __restrict__ ml_lfc2_b,
    const float* __restrict__ em_w, const float* __restrict__ em_b,
    const int* __restrict__ recv_idx, const int* __restrict__ send_idx,
    const float* __restrict__ ws, float* __restrict__ out) {

    const int be = blockIdx.x;           /* 0 .. B*NE-1 */
    const int b  = be / NE_;
    const int e  = be % NE_;
    const int tid  = threadIdx.x;
    const int lane = tid & 63;
    const int wv   = tid >> 6;           /* 0..3 */

    __shared__ float x_s[F_][TSTR];
    __shared__ float h_s[F_][TSTR];
    __shared__ float x0_s[8][TSTR];
    __shared__ float lat_s[64];
    __shared__ float cond_s[256];        /* g1 | b1 | g2 | b2 */
    __shared__ float red_s[4][64];
    __shared__ float vec_s[64];
    __shared__ float tmp_s[64];

    /* ---- stage 0: zero pads, gather inputs ---- */
    {
        const int row = tid >> 2, c = tid & 3;
        const int col = (c < 2) ? c : (50 + c);          /* 0,1,52,53 */
        x_s[row][col] = 0.f;
        h_s[row][col] = 0.f;
        if (tid < 32) {
            const int r8 = tid >> 2, c8 = tid & 3;
            const int col8 = (c8 < 2) ? c8 : (50 + c8);
            x0_s[r8][col8] = 0.f;
        }
    }
    const int recv = recv_idx[e];
    const int send = send_idx[e];
    for (int i = tid; i < 8 * T_; i += 256) {
        const int c = i / T_, t = i % T_;
        const float v = (c < 4)
            ? states[((b*NO_ + recv)*T_ + t)*SD_ + c]
            : states[((b*NO_ + send)*T_ + t)*SD_ + (c - 4)];
        x0_s[c][t + 2] = v;
    }
    if (tid < 64) lat_s[tid] = latent[(b*NE_ + e)*L_ + tid];
    __syncthreads();

    /* ---- stage 1: conv0 8->64, k=3, pad=1, swish ---- */
    {
        const int t0 = wv * 13;
        float acc[13];
        const float bias = cnnbf_b[lane];
#pragma unroll
        for (int j = 0; j < 13; ++j) acc[j] = bias;
        const float* w0t = ws + OFF_W0T;
#pragma unroll
        for (int fi = 0; fi < 8; ++fi) {
            float xr[15];
#pragma unroll
            for (int m = 0; m < 15; ++m) xr[m] = x0_s[fi][t0 + 1 + m];
#pragma unroll
            for (int k = 0; k < 3; ++k) {
                const float w = w0t[(fi*3 + k)*64 + lane];
#pragma unroll
                for (int j = 0; j < 13; ++j) acc[j] += w * xr[j + k];
            }
        }
#pragma unroll
        for (int j = 0; j < 13; ++j) {
            const int t = t0 + j;
            if (t < T_) x_s[lane][t + 2] = swish_(acc[j]);
        }
    }

    /* ---- stage 2: two conditional residual blocks ---- */
    for (int rb = 0; rb < 2; ++rb) {
        __syncthreads();
        {   /* latent conditioning: threads 0..127 -> l1, 128..255 -> l2 */
            const int which = tid >> 7, o = tid & 127;
            const float* Wt = ws + (which ? OFF_RBL2 : OFF_RBL1) + rb * 64 * 128;
            const float* bb = (which ? rb_lfc2_b : rb_lfc1_b) + rb * 128;
            float a = bb[o];
#pragma unroll 8
            for (int j = 0; j < 64; ++j) a += lat_s[j] * Wt[j*128 + o];
            cond_s[which*128 + o] = a;
        }
        __syncthreads();
        conv5_block<false>(x_s, h_s, ws + OFF_C1T + rb*320*64, rb_conv1_b + rb*64,
                           cond_s[lane], cond_s[64 + lane], lane, wv);
        __syncthreads();
        conv5_block<true>(h_s, x_s, ws + OFF_C2T + rb*320*64, rb_conv2_b + rb*64,
                          cond_s[128 + lane], cond_s[192 + lane], lane, wv);
    }
    __syncthreads();

    /* ---- stage 3: windowed MLP fc1 + swish, folded mean, fc2 ---- */
    {
        float part = 0.f;
        const float* fc1t = ws + OFF_FC1T;
        const float bias = mlp1_fc1_b[lane];
        for (int nw = wv; nw < NW_; nw += 4) {   /* wave-uniform nw */
            float a = bias;
            for (int f = 0; f < 64; ++f) {
                float xr[8];
#pragma unroll
                for (int k = 0; k < 8; ++k) xr[k] = x_s[f][nw*3 + 2 + k];
#pragma unroll
                for (int k = 0; k < 8; ++k) a += xr[k] * fc1t[(f*8 + k)*64 + lane];
            }
            part += swish_(a);
        }
        red_s[wv][lane] = part;
    }
    __syncthreads();
    if (tid < 64) {
        vec_s[tid] = (red_s[0][tid] + red_s[1][tid] + red_s[2][tid] + red_s[3][tid])
                     * (1.f / 15.f);             /* hbar = mean over windows */
    }
    __syncthreads();
    if (tid < 64) {
        const float* fc2t = ws + OFF_FC2T;
        float a = mlp1_fc2_b[tid];
#pragma unroll 8
        for (int fi = 0; fi < 64; ++fi) a += vec_s[fi] * fc2t[fi*64 + tid];
        tmp_s[tid] = a;
    }
    __syncthreads();
    if (tid < 64) vec_s[tid] = tmp_s[tid];

    /* ---- stage 4: three conditional MLP blocks ---- */
    for (int mb = 0; mb < 3; ++mb) {
        __syncthreads();
        {   /* latent conditioning */
            const int which = tid >> 7, o = tid & 127;
            const float* Wt = ws + (which ? OFF_MLL2 : OFF_MLL1) + mb * 64 * 128;
            const float* bb = (which ? ml_lfc2_b : ml_lfc1_b) + mb * 128;
            float a = bb[o];
#pragma unroll 8
            for (int j = 0; j < 64; ++j) a += lat_s[j] * Wt[j*128 + o];
            cond_s[which*128 + o] = a;
        }
        __syncthreads();
        if (tid < 64) {
            const float* W = ws + OFF_MLF1 + mb * 4096;
            float a = ml_fc1_b[mb*64 + tid];
#pragma unroll 8
            for (int j = 0; j < 64; ++j) a += vec_s[j] * W[j*64 + tid];
            const float v = cond_s[tid] * a + cond_s[64 + tid];
            tmp_s[tid] = swish_(v);
        }
        __syncthreads();
        if (tid < 64) {
            const float* W = ws + OFF_MLF2 + mb * 4096;
            float a = ml_fc2_b[mb*64 + tid];
#pragma unroll 8
            for (int j = 0; j < 64; ++j) a += tmp_s[j] * W[j*64 + tid];
            const float v = cond_s[128 + tid] * a + cond_s[192 + tid];
            vec_s[tid] += swish_(v);
        }
    }
    __syncthreads();

    /* ---- stage 5: energy head ---- */
    if (wv == 0) {
        float p = vec_s[lane] * em_w[lane];
#pragma unroll
        for (int off = 32; off > 0; off >>= 1) p += __shfl_down(p, off);
        if (lane == 0) out[be] = p + em_b[0];
    }
}

extern "C" void kernel_launch(void* const* d_in, const int* in_sizes, int n_in,
                              void* d_out, int out_size, void* d_ws, size_t ws_size,
                              hipStream_t stream) {
    const float* states   = (const float*)d_in[0];
    const float* latent   = (const float*)d_in[1];
    const float* cnnbf_w  = (const float*)d_in[2];
    const float* cnnbf_b  = (const float*)d_in[3];
    const float* rb1w     = (const float*)d_in[4];
    const float* rb1b     = (const float*)d_in[5];
    const float* rb2w     = (const float*)d_in[6];
    const float* rb2b     = (const float*)d_in[7];
    const float* rbl1w    = (const float*)d_in[8];
    const float* rbl1b    = (const float*)d_in[9];
    const float* rbl2w    = (const float*)d_in[10];
    const float* rbl2b    = (const float*)d_in[11];
    const float* fc1w     = (const float*)d_in[12];
    const float* fc1b     = (const float*)d_in[13];
    const float* fc2w     = (const float*)d_in[14];
    const float* fc2b     = (const float*)d_in[15];
    const float* mlf1w    = (const float*)d_in[16];
    const float* mlf1b    = (const float*)d_in[17];
    const float* mlf2w    = (const float*)d_in[18];
    const float* mlf2b    = (const float*)d_in[19];
    const float* mll1w    = (const float*)d_in[20];
    const float* mll1b    = (const float*)d_in[21];
    const float* mll2w    = (const float*)d_in[22];
    const float* mll2b    = (const float*)d_in[23];
    const float* em_w     = (const float*)d_in[24];
    const float* em_b     = (const float*)d_in[25];
    const int*   recv_idx = (const int*)d_in[26];
    const int*   send_idx = (const int*)d_in[27];
    float* ws  = (float*)d_ws;
    float* out = (float*)d_out;

    prep_kernel<<<(WS_TOTAL + 255) / 256, 256, 0, stream>>>(
        cnnbf_w, rb1w, rb2w, fc1w, fc2w, rbl1w, rbl2w, mll1w, mll2w, mlf1w, mlf2w, ws);

    mega_kernel<<<B_ * NE_, 256, 0, stream>>>(
        states, latent, cnnbf_b, rb1b, rb2b, rbl1b, rbl2b, fc1b, fc2b,
        mlf1b, mlf2b, mll1b, mll2b, em_w, em_b, recv_idx, send_idx, ws, out);
}

// Round 2
// 1037.990 us; speedup vs baseline: 3.2901x; 3.2901x over previous
//
#include <hip/hip_runtime.h>

#define B_      2
#define NO_     96
#define T_      50
#define SD_     4
#define NE_     (NO_*(NO_-1))   /* 9120 */
#define F_      64
#define L_      64
#define NW_     15

typedef __attribute__((ext_vector_type(8))) short  short8;   /* bf16x8 MFMA frag */
typedef __attribute__((ext_vector_type(4))) float  f32x4;
typedef __attribute__((ext_vector_type(4))) unsigned short u16x4;

/* ---- ws layout ----
   [0, 6144)      : conv0 weights fp32, w0t[(fi*3+k)*64+fo]            (1536 f)
   [8192, ...)    : bf16 pool (ushort), element offsets below           */
#define E_CONVA 0        /* [4 conv][4 m][10 kk][64 lane][8]  = 81920  */
#define E_FC1A  81920    /* [4 m][16 kk][64 lane][8]          = 32768  */
#define E_RBL   114688   /* [2 rb][2 which][64 j][128 o]      = 32768  */
#define E_MLL   147456   /* [3 i][2 which][64 j][128 o]       = 49152  */
#define E_MLF   196608   /* [3 i][2 which][64 j][64 o]        = 24576  */
#define E_FC2T  221184   /* [64 fi][64 o]                     = 4096   */
#define N_BF16  225280
#define N_PREP  (1536 + N_BF16)

__device__ __forceinline__ float swish_(float v) { return v / (1.f + __expf(-v)); }

__device__ __forceinline__ unsigned short f2bf(float f) {
    unsigned u = __float_as_uint(f);
    u += 0x7FFFu + ((u >> 16) & 1u);          /* round-to-nearest-even */
    return (unsigned short)(u >> 16);
}
__device__ __forceinline__ float bf2f(unsigned short u) {
    return __uint_as_float(((unsigned)u) << 16);
}

/* ------------------------------------------------------------------ */
__global__ void prep_kernel(const float* __restrict__ cnnbf_w,
                            const float* __restrict__ rb1w, const float* __restrict__ rb2w,
                            const float* __restrict__ fc1w, const float* __restrict__ fc2w,
                            const float* __restrict__ rbl1w, const float* __restrict__ rbl2w,
                            const float* __restrict__ mll1w, const float* __restrict__ mll2w,
                            const float* __restrict__ mlf1w, const float* __restrict__ mlf2w,
                            float* __restrict__ ws) {
    int idx = blockIdx.x * blockDim.x + threadIdx.x;
    if (idx >= N_PREP) return;
    if (idx < 1536) {                               /* conv0, fp32, [fi*3+k][fo] */
        int fo = idx & 63, q = idx >> 6, fi = q / 3, k = q % 3;
        ws[idx] = cnnbf_w[(fo*8 + fi)*3 + k];
        return;
    }
    int e = idx - 1536;
    unsigned short* bfp = (unsigned short*)((char*)ws + 8192);
    float v;
    if (e < E_FC1A) {                               /* conv A frags */
        int r = e & 511, fid = e >> 9;
        int lane = r >> 3, j = r & 7;
        int kk = fid % 10, m = (fid / 10) & 3, c = fid / 40;
        int fo = m*16 + (lane & 15);
        int kidx = kk*32 + (lane >> 4)*8 + j;
        int k = kidx >> 6, fi = kidx & 63;
        int i = c >> 1;
        const float* src = (c & 1) ? rb2w : rb1w;
        v = src[((i*64 + fo)*64 + fi)*5 + k];
    } else if (e < E_RBL) {                         /* fc1 A frags */
        int e2 = e - E_FC1A;
        int r = e2 & 511, fid = e2 >> 9;
        int lane = r >> 3, j = r & 7;
        int kk = fid & 15, m = fid >> 4;
        int fo = m*16 + (lane & 15);
        int krow = kk*32 + (lane >> 4)*8 + j;
        v = fc1w[fo*512 + krow];
    } else if (e < E_MLL) {                         /* rb cond weights [j][o] */
        int e3 = e - E_RBL;
        int o = e3 & 127, j = (e3 >> 7) & 63, which = (e3 >> 13) & 1, rb = e3 >> 14;
        const float* src = which ? rbl2w : rbl1w;
        v = src[(rb*128 + o)*64 + j];
    } else if (e < E_MLF) {                         /* ml cond weights */
        int e4 = e - E_MLL;
        int o = e4 & 127, j = (e4 >> 7) & 63, which = (e4 >> 13) & 1, i = e4 >> 14;
        const float* src = which ? mll2w : mll1w;
        v = src[(i*128 + o)*64 + j];
    } else if (e < E_FC2T) {                        /* ml fc weights [j][o] */
        int e5 = e - E_MLF;
        int o = e5 & 63, j = (e5 >> 6) & 63, which = (e5 >> 12) & 1, i = e5 >> 13;
        const float* src = which ? mlf2w : mlf1w;
        v = src[(i*64 + o)*64 + j];
    } else {                                        /* fc2 [fi][o] */
        int e6 = e - E_FC2T;
        int o = e6 & 63, fi = e6 >> 6;
        v = fc2w[o*64 + fi];
    }
    bfp[e] = f2bf(v);
}

/* ---------------- conv 64->64 k=5 via MFMA -------------------------
   Wave wv owns M-tile (16 fo). N covered by tiles t0 = {0,16,32,34};
   tile 3 duplicates cols 34..47 (epilogue predicated to row0>=14).
   B source: swizzled bf16 [54 rows][64 fi]; row = t + k (x stored at +2). */
template<bool ISCONV2>
__device__ __forceinline__ void convpass(const short8* __restrict__ Af,
                                         const unsigned short* __restrict__ Bsrc,
                                         unsigned short* __restrict__ Dst,
                                         float* __restrict__ xm,        /* [50][64] fp32 master */
                                         const float* __restrict__ cbg, /* conv bias + rb*64 */
                                         const float* __restrict__ gv,
                                         const float* __restrict__ bv,
                                         int lane, int wv) {
    const int row0 = lane & 15;
    const int g0   = lane >> 4;
    const int fo0  = wv*16 + g0*4;
    f32x4 acc0 = {0.f,0.f,0.f,0.f}, acc1 = acc0, acc2 = acc0, acc3 = acc0;
#pragma unroll
    for (int kk = 0; kk < 10; ++kk) {
        short8 a = Af[(wv*10 + kk)*64 + lane];
        const int s  = row0 + (kk >> 1);
        const int g  = g0 + ((kk & 1) << 2);
        const int i0 = s*64 + ((g ^ (s & 7)) << 3);
        short8 b0 = *(const short8*)&Bsrc[i0];
        short8 b1 = *(const short8*)&Bsrc[i0 + 1024];
        short8 b2 = *(const short8*)&Bsrc[i0 + 2048];
        const int r3 = s + 34;
        short8 b3 = *(const short8*)&Bsrc[r3*64 + ((g ^ (r3 & 7)) << 3)];
        acc0 = __builtin_amdgcn_mfma_f32_16x16x32_bf16(a, b0, acc0, 0, 0, 0);
        acc1 = __builtin_amdgcn_mfma_f32_16x16x32_bf16(a, b1, acc1, 0, 0, 0);
        acc2 = __builtin_amdgcn_mfma_f32_16x16x32_bf16(a, b2, acc2, 0, 0, 0);
        acc3 = __builtin_amdgcn_mfma_f32_16x16x32_bf16(a, b3, acc3, 0, 0, 0);
    }
    const f32x4 cb4 = *(const f32x4*)&cbg[fo0];
    const f32x4 g4  = *(const f32x4*)&gv[fo0];
    const f32x4 b4  = *(const f32x4*)&bv[fo0];
#pragma unroll
    for (int n = 0; n < 4; ++n) {
        const int tb = (n == 3) ? 34 : n * 16;
        const int t  = tb + row0;
        if (n == 3 && row0 < 14) continue;          /* duplicated columns */
        const f32x4 A = (n == 0) ? acc0 : (n == 1) ? acc1 : (n == 2) ? acc2 : acc3;
        float w0, w1, w2, w3;
        {
            float s0 = swish_(g4[0]*(A[0] + cb4[0]) + b4[0]);
            float s1 = swish_(g4[1]*(A[1] + cb4[1]) + b4[1]);
            float s2 = swish_(g4[2]*(A[2] + cb4[2]) + b4[2]);
            float s3 = swish_(g4[3]*(A[3] + cb4[3]) + b4[3]);
            if (ISCONV2) {
                f32x4 x4 = *(f32x4*)&xm[t*64 + fo0];
                x4[0] += s0; x4[1] += s1; x4[2] += s2; x4[3] += s3;
                *(f32x4*)&xm[t*64 + fo0] = x4;
                w0 = x4[0]; w1 = x4[1]; w2 = x4[2]; w3 = x4[3];
            } else { w0 = s0; w1 = s1; w2 = s2; w3 = s3; }
        }
        const int row = t + 2;
        const int dix = row*64 + ((((fo0 >> 3) ^ (row & 7))) << 3) + (fo0 & 7);
        u16x4 q; q[0] = f2bf(w0); q[1] = f2bf(w1); q[2] = f2bf(w2); q[3] = f2bf(w3);
        *(u16x4*)&Dst[dix] = q;
    }
}

/* ------------------------------------------------------------------ */
__global__ __launch_bounds__(256) void mega_kernel(
    const float* __restrict__ states, const float* __restrict__ latent,
    const float* __restrict__ cnnbf_b,
    const float* __restrict__ rb_conv1_b, const float* __restrict__ rb_conv2_b,
    const float* __restrict__ rb_lfc1_b, const float* __restrict__ rb_lfc2_b,
    const float* __restrict__ mlp1_fc1_b, const float* __restrict__ mlp1_fc2_b,
    const float* __restrict__ ml_fc1_b, const float* __restrict__ ml_fc2_b,
    const float* __restrict__ ml_lfc1_b, const float* __restrict__ ml_lfc2_b,
    const float* __restrict__ em_w, const float* __restrict__ em_b,
    const int* __restrict__ recv_idx, const int* __restrict__ send_idx,
    const float* __restrict__ ws, float* __restrict__ out) {

    const int be = blockIdx.x;
    const int b  = be / NE_;
    const int e  = be % NE_;
    const int tid  = threadIdx.x;
    const int lane = tid & 63;
    const int wv   = tid >> 6;

    __shared__ __align__(16) float x_sT[50][64];            /* fp32 master, [t][fo] */
    __shared__ __align__(16) unsigned short xT[54*64];      /* bf16 swizzled [row][fi] */
    __shared__ __align__(16) unsigned short hT[54*64];
    __shared__ __align__(16) float x0_s[8][56];
    __shared__ float lat_s[64];
    __shared__ __align__(16) float cond_s[256];
    __shared__ __align__(16) float vec_s[64];
    __shared__ float tmp_s[64];

    const unsigned short* bfp = (const unsigned short*)((const char*)ws + 8192);
    const short8* AF = (const short8*)bfp;                  /* frag i = elems [8i,8i+8) */

    /* ---- stage 0 ---- */
    {   /* zero bf16 pad rows 0,1,52,53 */
        int r = tid >> 6; int row = (r < 2) ? r : 50 + r;
        xT[row*64 + (tid & 63)] = 0;
        hT[row*64 + (tid & 63)] = 0;
        if (tid < 32) {
            int r8 = tid >> 2, c8 = tid & 3;
            x0_s[r8][(c8 < 2) ? c8 : (50 + c8)] = 0.f;
        }
    }
    const int recv = recv_idx[e];
    const int send = send_idx[e];
    for (int i = tid; i < 8 * T_; i += 256) {
        const int c = i / T_, t = i % T_;
        const float v = (c < 4)
            ? states[((b*NO_ + recv)*T_ + t)*SD_ + c]
            : states[((b*NO_ + send)*T_ + t)*SD_ + (c - 4)];
        x0_s[c][t + 2] = v;
    }
    if (tid < 64) lat_s[tid] = latent[(b*NE_ + e)*L_ + tid];
    __syncthreads();

    /* ---- stage 1: conv0 8->64 k=3, fp32 VALU ---- */
    {
        const int t0 = wv * 13;
        float acc[13];
        const float bias = cnnbf_b[lane];
#pragma unroll
        for (int j = 0; j < 13; ++j) acc[j] = bias;
        const float* w0t = ws;
#pragma unroll
        for (int fi = 0; fi < 8; ++fi) {
            float xr[15];
#pragma unroll
            for (int m = 0; m < 15; ++m) xr[m] = x0_s[fi][t0 + 1 + m];
#pragma unroll
            for (int k = 0; k < 3; ++k) {
                const float w = w0t[(fi*3 + k)*64 + lane];
#pragma unroll
                for (int j = 0; j < 13; ++j) acc[j] += w * xr[j + k];
            }
        }
#pragma unroll
        for (int j = 0; j < 13; ++j) {
            const int t = t0 + j;
            if (t < T_) {
                const float v = swish_(acc[j]);
                x_sT[t][lane] = v;
                const int row = t + 2;
                xT[row*64 + (((lane >> 3) ^ (row & 7)) << 3) + (lane & 7)] = f2bf(v);
            }
        }
    }

    /* ---- stage 2: residual blocks ---- */
    for (int rb = 0; rb < 2; ++rb) {
        __syncthreads();
        {   /* latent conditioning, bf16 weights */
            const int which = tid >> 7, o = tid & 127;
            const unsigned short* W = bfp + E_RBL + (rb*2 + which)*8192 + o;
            float a = (which ? rb_lfc2_b : rb_lfc1_b)[rb*128 + o];
#pragma unroll 16
            for (int j = 0; j < 64; ++j) a += lat_s[j] * bf2f(W[j*128]);
            cond_s[which*128 + o] = a;
        }
        __syncthreads();
        convpass<false>(AF + (rb*2 + 0)*2560, xT, hT, nullptr,
                        rb_conv1_b + rb*64, cond_s, cond_s + 64, lane, wv);
        __syncthreads();
        convpass<true>(AF + (rb*2 + 1)*2560, hT, xT, &x_sT[0][0],
                       rb_conv2_b + rb*64, cond_s + 128, cond_s + 192, lane, wv);
    }
    __syncthreads();

    /* ---- stage 3: windowed MLP fc1 via MFMA, folded mean, fc2 ---- */
    {
        const int h = lane >> 4, nw = lane & 15;
        f32x4 acc = {0.f,0.f,0.f,0.f};
        const int nwe = (nw < 15) ? nw : 14;        /* lane 15 duplicates, discarded */
        const int nwrow = 3*nwe + 2;
#pragma unroll
        for (int kk = 0; kk < 16; ++kk) {
            short8 a = AF[10240 + (wv*16 + kk)*64 + lane];
            const int f = kk*4 + h, gq = f >> 3, f7 = f & 7;
            short8 bfr;
#pragma unroll
            for (int j = 0; j < 8; ++j) {
                const int row = nwrow + j;
                bfr[j] = (short)xT[row*64 + ((gq ^ (row & 7)) << 3) + f7];
            }
            acc = __builtin_amdgcn_mfma_f32_16x16x32_bf16(a, bfr, acc, 0, 0, 0);
        }
        const f32x4 fb = *(const f32x4*)&mlp1_fc1_b[wv*16 + h*4];
        float red[4];
#pragma unroll
        for (int r = 0; r < 4; ++r) {
            float v = (nw < 15) ? swish_(acc[r] + fb[r]) : 0.f;
            v += __shfl_xor(v, 1); v += __shfl_xor(v, 2);
            v += __shfl_xor(v, 4); v += __shfl_xor(v, 8);
            red[r] = v * (1.f / 15.f);
        }
        if (nw == 0) {
            f32x4 o4; o4[0] = red[0]; o4[1] = red[1]; o4[2] = red[2]; o4[3] = red[3];
            *(f32x4*)&vec_s[wv*16 + h*4] = o4;
        }
    }
    __syncthreads();
    if (tid < 64) {                                  /* fc2, bf16 weights */
        const unsigned short* W = bfp + E_FC2T + tid;
        float a = mlp1_fc2_b[tid];
#pragma unroll 16
        for (int fi = 0; fi < 64; ++fi) a += vec_s[fi] * bf2f(W[fi*64]);
        tmp_s[tid] = a;
    }
    __syncthreads();
    if (tid < 64) vec_s[tid] = tmp_s[tid];

    /* ---- stage 4: conditional MLP blocks ---- */
    for (int mb = 0; mb < 3; ++mb) {
        __syncthreads();
        {
            const int which = tid >> 7, o = tid & 127;
            const unsigned short* W = bfp + E_MLL + (mb*2 + which)*8192 + o;
            float a = (which ? ml_lfc2_b : ml_lfc1_b)[mb*128 + o];
#pragma unroll 16
            for (int j = 0; j < 64; ++j) a += lat_s[j] * bf2f(W[j*128]);
            cond_s[which*128 + o] = a;
        }
        __syncthreads();
        if (tid < 64) {
            const unsigned short* W = bfp + E_MLF + (mb*2 + 0)*4096 + tid;
            float a = ml_fc1_b[mb*64 + tid];
#pragma unroll 16
            for (int j = 0; j < 64; ++j) a += vec_s[j] * bf2f(W[j*64]);
            tmp_s[tid] = swish_(cond_s[tid] * a + cond_s[64 + tid]);
        }
        __syncthreads();
        if (tid < 64) {
            const unsigned short* W = bfp + E_MLF + (mb*2 + 1)*4096 + tid;
            float a = ml_fc2_b[mb*64 + tid];
#pragma unroll 16
            for (int j = 0; j < 64; ++j) a += tmp_s[j] * bf2f(W[j*64]);
            vec_s[tid] += swish_(cond_s[128 + tid] * a + cond_s[192 + tid]);
        }
    }
    __syncthreads();

    /* ---- stage 5: energy head ---- */
    if (wv == 0) {
        float p = vec_s[lane] * em_w[lane];
#pragma unroll
        for (int off = 32; off > 0; off >>= 1) p += __shfl_down(p, off);
        if (lane == 0) out[be] = p + em_b[0];
    }
}

extern "C" void kernel_launch(void* const* d_in, const int* in_sizes, int n_in,
                              void* d_out, int out_size, void* d_ws, size_t ws_size,
                              hipStream_t stream) {
    const float* states   = (const float*)d_in[0];
    const float* latent   = (const float*)d_in[1];
    const float* cnnbf_w  = (const float*)d_in[2];
    const float* cnnbf_b  = (const float*)d_in[3];
    const float* rb1w     = (const float*)d_in[4];
    const float* rb1b     = (const float*)d_in[5];
    const float* rb2w     = (const float*)d_in[6];
    const float* rb2b     = (const float*)d_in[7];
    const float* rbl1w    = (const float*)d_in[8];
    const float* rbl1b    = (const float*)d_in[9];
    const float* rbl2w    = (const float*)d_in[10];
    const float* rbl2b    = (const float*)d_in[11];
    const float* fc1w     = (const float*)d_in[12];
    const float* fc1b     = (const float*)d_in[13];
    const float* fc2w     = (const float*)d_in[14];
    const float* fc2b     = (const float*)d_in[15];
    const float* mlf1w    = (const float*)d_in[16];
    const float* mlf1b    = (const float*)d_in[17];
    const float* mlf2w    = (const float*)d_in[18];
    const float* mlf2b    = (const float*)d_in[19];
    const float* mll1w    = (const float*)d_in[20];
    const float* mll1b    = (const float*)d_in[21];
    const float* mll2w    = (const float*)d_in[22];
    const float* mll2b    = (const float*)d_in[23];
    const float* em_w     = (const float*)d_in[24];
    const float* em_b     = (const float*)d_in[25];
    const int*   recv_idx = (const int*)d_in[26];
    const int*   send_idx = (const int*)d_in[27];
    float* ws  = (float*)d_ws;
    float* out = (float*)d_out;

    prep_kernel<<<(N_PREP + 255) / 256, 256, 0, stream>>>(
        cnnbf_w, rb1w, rb2w, fc1w, fc2w, rbl1w, rbl2w, mll1w, mll2w, mlf1w, mlf2w, ws);

    mega_kernel<<<B_ * NE_, 256, 0, stream>>>(
        states, latent, cnnbf_b, rb1b, rb2b, rbl1b, rbl2b, fc1b, fc2b,
        mlf1b, mlf2b, mll1b, mll2b, em_w, em_b, recv_idx, send_idx, ws, out);
}

// Round 3
// 616.900 us; speedup vs baseline: 5.5360x; 1.6826x over previous
//
#include <hip/hip_runtime.h>

#define B_      2
#define NO_     96
#define T_      50
#define SD_     4
#define NE_     (NO_*(NO_-1))   /* 9120 */
#define F_      64
#define NW_     15

typedef __attribute__((ext_vector_type(8))) short  short8;   /* bf16x8 MFMA frag */
typedef __attribute__((ext_vector_type(4))) float  f32x4;
typedef __attribute__((ext_vector_type(4))) unsigned short u16x4;

/* ---- ws layout ----
   fp32 [0,1536): conv0 weights w0t[(fi*3+k)*64+fo]
   byte 8192: bf16 pool (ushort), element offsets:          */
#define E_CONVA 0        /* [4 conv][4 m][10 kk][64][8]   = 81920 */
#define E_FC1A  81920    /* [4 m][16 kk][64][8] k=kt*64+f = 32768 */
#define E_RBL   114688   /* [2 rb][2 which][64 j][128 o]  = 32768 */
#define E_CONDP 147456   /* [3 mb][16 nt][2 kk][64][8]    = 49152 */
#define E_FCP   196608   /* [7 g][4 nt][2 kk][64][8]      = 28672 */
#define N_BF16  225280
#define N_PREP  (1536 + N_BF16)
#define HBAR_F32 114688          /* float offset: (8192 + 2*N_BF16)/4 */

__device__ __forceinline__ float swish_(float v) { return v / (1.f + __expf(-v)); }

__device__ __forceinline__ unsigned short f2bf(float f) {
    unsigned u = __float_as_uint(f);
    u += 0x7FFFu + ((u >> 16) & 1u);
    return (unsigned short)(u >> 16);
}
__device__ __forceinline__ float bf2f(unsigned short u) {
    return __uint_as_float(((unsigned)u) << 16);
}

/* ------------------------------------------------------------------ */
__global__ void prep_kernel(const float* __restrict__ cnnbf_w,
                            const float* __restrict__ rb1w, const float* __restrict__ rb2w,
                            const float* __restrict__ fc1w, const float* __restrict__ fc2w,
                            const float* __restrict__ rbl1w, const float* __restrict__ rbl2w,
                            const float* __restrict__ mll1w, const float* __restrict__ mll2w,
                            const float* __restrict__ mlf1w, const float* __restrict__ mlf2w,
                            float* __restrict__ ws) {
    int idx = blockIdx.x * blockDim.x + threadIdx.x;
    if (idx >= N_PREP) return;
    if (idx < 1536) {                               /* conv0 fp32 */
        int fo = idx & 63, q = idx >> 6, fi = q / 3, k = q % 3;
        ws[idx] = cnnbf_w[(fo*8 + fi)*3 + k];
        return;
    }
    int e = idx - 1536;
    unsigned short* bfp = (unsigned short*)((char*)ws + 8192);
    float v;
    if (e < E_FC1A) {                               /* conv A frags (k = tap*64+fi) */
        int r = e & 511, fid = e >> 9;
        int lane = r >> 3, j = r & 7;
        int kk = fid % 10, m = (fid / 10) & 3, c = fid / 40;
        int fo = m*16 + (lane & 15);
        int kidx = kk*32 + (lane >> 4)*8 + j;
        int k = kidx >> 6, fi = kidx & 63;
        int i = c >> 1;
        const float* src = (c & 1) ? rb2w : rb1w;
        v = src[((i*64 + fo)*64 + fi)*5 + k];
    } else if (e < E_RBL) {                         /* fc1 A frags, k = kt*64+f (time-major) */
        int e2 = e - E_FC1A;
        int r = e2 & 511, fid = e2 >> 9;
        int lane = r >> 3, j = r & 7;
        int kk = fid & 15, m = fid >> 4;
        int fo = m*16 + (lane & 15);
        int k = kk*32 + (lane >> 4)*8 + j;
        int krow = (k & 63)*8 + (k >> 6);           /* original index = f*8 + kt */
        v = fc1w[fo*512 + krow];
    } else if (e < E_CONDP) {                       /* rb cond weights [j][o] */
        int e3 = e - E_RBL;
        int o = e3 & 127, j = (e3 >> 7) & 63, which = (e3 >> 13) & 1, rb = e3 >> 14;
        const float* src = which ? rbl2w : rbl1w;
        v = src[(rb*128 + o)*64 + j];
    } else if (e < E_FCP) {                         /* mb cond B frags */
        int e4 = e - E_CONDP;
        int r = e4 & 511, fid = e4 >> 9;            /* fid = (mb*16+nt)*2+kk */
        int lane = r >> 3, j = r & 7;
        int kk = fid & 1, nt = (fid >> 1) & 15, mb = fid >> 5;
        int n = nt*16 + (lane & 15);
        int which = n >> 7, o = n & 127;
        int k = kk*32 + (lane >> 4)*8 + j;
        const float* src = which ? mll2w : mll1w;
        v = src[(mb*128 + o)*64 + k];
    } else {                                        /* tail fc B frags */
        int e5 = e - E_FCP;
        int r = e5 & 511, fid = e5 >> 9;            /* fid = (g*4+nt)*2+kk */
        int lane = r >> 3, j = r & 7;
        int kk = fid & 1, nt = (fid >> 1) & 3, g = fid >> 3;
        int o = nt*16 + (lane & 15);
        int k = kk*32 + (lane >> 4)*8 + j;
        if (g == 0) v = fc2w[o*64 + k];
        else {
            int mb = (g - 1) >> 1;
            const float* src = ((g - 1) & 1) ? mlf2w : mlf1w;
            v = src[(mb*64 + o)*64 + k];
        }
    }
    bfp[e] = f2bf(v);
}

/* ---------------- conv 64->64 k=5 via MFMA -------------------------
   xT/hT: bf16 swizzled [54 rows][64 fi], slot' = slot ^ (row&7).
   ISCONV2: residual accumulate into Dst (== trunk xT). */
template<bool ISCONV2>
__device__ __forceinline__ void convpass(const short8* __restrict__ Af,
                                         const unsigned short* __restrict__ Bsrc,
                                         unsigned short* __restrict__ Dst,
                                         const float* __restrict__ cb,
                                         const float* __restrict__ gv,
                                         const float* __restrict__ bv,
                                         int lane, int wv) {
    const int row0 = lane & 15;
    const int g0   = lane >> 4;
    const int fo0  = wv*16 + g0*4;
    f32x4 acc0 = {0.f,0.f,0.f,0.f}, acc1 = acc0, acc2 = acc0, acc3 = acc0;
#pragma unroll
    for (int kk = 0; kk < 10; ++kk) {
        short8 a = Af[(wv*10 + kk)*64 + lane];
        const int s  = row0 + (kk >> 1);
        const int g  = g0 + ((kk & 1) << 2);
        const int i0 = s*64 + ((g ^ (s & 7)) << 3);
        short8 b0 = *(const short8*)&Bsrc[i0];
        short8 b1 = *(const short8*)&Bsrc[i0 + 1024];
        short8 b2 = *(const short8*)&Bsrc[i0 + 2048];
        const int r3 = s + 34;
        short8 b3 = *(const short8*)&Bsrc[r3*64 + ((g ^ (r3 & 7)) << 3)];
        acc0 = __builtin_amdgcn_mfma_f32_16x16x32_bf16(a, b0, acc0, 0, 0, 0);
        acc1 = __builtin_amdgcn_mfma_f32_16x16x32_bf16(a, b1, acc1, 0, 0, 0);
        acc2 = __builtin_amdgcn_mfma_f32_16x16x32_bf16(a, b2, acc2, 0, 0, 0);
        acc3 = __builtin_amdgcn_mfma_f32_16x16x32_bf16(a, b3, acc3, 0, 0, 0);
    }
    const f32x4 cb4 = *(const f32x4*)&cb[fo0];
    const f32x4 g4  = *(const f32x4*)&gv[fo0];
    const f32x4 b4  = *(const f32x4*)&bv[fo0];
#pragma unroll
    for (int n = 0; n < 4; ++n) {
        const int tb = (n == 3) ? 34 : n * 16;
        const int t  = tb + row0;
        if (n == 3 && row0 < 14) continue;
        const f32x4 A = (n == 0) ? acc0 : (n == 1) ? acc1 : (n == 2) ? acc2 : acc3;
        float s0 = swish_(g4[0]*(A[0] + cb4[0]) + b4[0]);
        float s1 = swish_(g4[1]*(A[1] + cb4[1]) + b4[1]);
        float s2 = swish_(g4[2]*(A[2] + cb4[2]) + b4[2]);
        float s3 = swish_(g4[3]*(A[3] + cb4[3]) + b4[3]);
        const int row = t + 2;
        const int dix = row*64 + ((((fo0 >> 3) ^ (row & 7))) << 3) + (fo0 & 7);
        if (ISCONV2) {                               /* residual RMW, own slot */
            u16x4 old = *(u16x4*)&Dst[dix];
            s0 += bf2f(old[0]); s1 += bf2f(old[1]);
            s2 += bf2f(old[2]); s3 += bf2f(old[3]);
        }
        u16x4 q; q[0] = f2bf(s0); q[1] = f2bf(s1); q[2] = f2bf(s2); q[3] = f2bf(s3);
        *(u16x4*)&Dst[dix] = q;
    }
}

/* ------------------------------------------------------------------ */
__global__ __launch_bounds__(256) void mega_kernel(
    const float* __restrict__ states, const float* __restrict__ latent,
    const float* __restrict__ cnnbf_b,
    const float* __restrict__ rb_conv1_b, const float* __restrict__ rb_conv2_b,
    const float* __restrict__ rb_lfc1_b, const float* __restrict__ rb_lfc2_b,
    const float* __restrict__ mlp1_fc1_b,
    const int* __restrict__ recv_idx, const int* __restrict__ send_idx,
    const float* __restrict__ ws, float* __restrict__ hbar) {

    const int be = blockIdx.x;
    const int b  = be / NE_;
    const int e  = be % NE_;
    const int tid  = threadIdx.x;
    const int lane = tid & 63;
    const int wv   = tid >> 6;

    __shared__ __align__(16) unsigned short xT[54*64];   /* bf16 trunk, swizzled */
    __shared__ __align__(16) unsigned short hT[54*64];
    __shared__ __align__(16) float x0_s[8][56];
    __shared__ float lat_s[64];
    __shared__ __align__(16) float cond_s[512];          /* [rb][g1|b1|g2|b2] */

    const unsigned short* bfp = (const unsigned short*)((const char*)ws + 8192);
    const short8* AF = (const short8*)bfp;

    /* ---- stage 0 ---- */
    {
        int r = tid >> 6; int row = (r < 2) ? r : 50 + r;
        xT[row*64 + (tid & 63)] = 0;
        hT[row*64 + (tid & 63)] = 0;
        if (tid < 32) {
            int r8 = tid >> 2, c8 = tid & 3;
            x0_s[r8][(c8 < 2) ? c8 : (50 + c8)] = 0.f;
        }
    }
    const int recv = recv_idx[e];
    const int send = send_idx[e];
    for (int i = tid; i < 8 * T_; i += 256) {
        const int c = i / T_, t = i % T_;
        const float v = (c < 4)
            ? states[((b*NO_ + recv)*T_ + t)*SD_ + c]
            : states[((b*NO_ + send)*T_ + t)*SD_ + (c - 4)];
        x0_s[c][t + 2] = v;
    }
    if (tid < 64) lat_s[tid] = latent[(b*NE_ + e)*64 + tid];
    __syncthreads();

    /* ---- stage 1a: conv0 8->64 k=3, fp32 VALU ---- */
    {
        const int t0 = wv * 13;
        float acc[13];
        const float bias = cnnbf_b[lane];
#pragma unroll
        for (int j = 0; j < 13; ++j) acc[j] = bias;
        const float* w0t = ws;
#pragma unroll
        for (int fi = 0; fi < 8; ++fi) {
            float xr[15];
#pragma unroll
            for (int m = 0; m < 15; ++m) xr[m] = x0_s[fi][t0 + 1 + m];
#pragma unroll
            for (int k = 0; k < 3; ++k) {
                const float w = w0t[(fi*3 + k)*64 + lane];
#pragma unroll
                for (int j = 0; j < 13; ++j) acc[j] += w * xr[j + k];
            }
        }
#pragma unroll
        for (int j = 0; j < 13; ++j) {
            const int t = t0 + j;
            if (t < T_) {
                const int row = t + 2;
                xT[row*64 + (((lane >> 3) ^ (row & 7)) << 3) + (lane & 7)]
                    = f2bf(swish_(acc[j]));
            }
        }
    }
    /* ---- stage 1b: BOTH rb conds (512 outputs, 2 per thread) ---- */
#pragma unroll
    for (int rep = 0; rep < 2; ++rep) {
        const int oid = tid + rep*256;
        const int rb = oid >> 8, rest = oid & 255, which = rest >> 7, o = rest & 127;
        const unsigned short* W = bfp + E_RBL + (rb*2 + which)*8192 + o;
        float a = (which ? rb_lfc2_b : rb_lfc1_b)[rb*128 + o];
#pragma unroll 16
        for (int j = 0; j < 64; ++j) a += lat_s[j] * bf2f(W[j*128]);
        cond_s[oid] = a;
    }
    __syncthreads();

    /* ---- stage 2: residual blocks ---- */
#pragma unroll 1
    for (int rb = 0; rb < 2; ++rb) {
        const float* cs = cond_s + rb*256;
        convpass<false>(AF + (rb*2 + 0)*2560, xT, hT,
                        rb_conv1_b + rb*64, cs, cs + 64, lane, wv);
        __syncthreads();
        convpass<true>(AF + (rb*2 + 1)*2560, hT, xT,
                       rb_conv2_b + rb*64, cs + 128, cs + 192, lane, wv);
        __syncthreads();
    }

    /* ---- stage 3: windowed MLP fc1 (k = kt*64+f) + folded mean ---- */
    {
        const int h = lane >> 4, nw = lane & 15;
        f32x4 acc = {0.f,0.f,0.f,0.f};
        const int nwe = (nw < 15) ? nw : 14;
        const int nwrow = 3*nwe + 2;
#pragma unroll
        for (int kk = 0; kk < 16; ++kk) {
            short8 a = AF[10240 + (wv*16 + kk)*64 + lane];
            const int row = nwrow + (kk >> 1);
            const int g   = ((kk & 1) << 2) + h;
            short8 bfr = *(const short8*)&xT[row*64 + ((g ^ (row & 7)) << 3)];
            acc = __builtin_amdgcn_mfma_f32_16x16x32_bf16(a, bfr, acc, 0, 0, 0);
        }
        const f32x4 fb = *(const f32x4*)&mlp1_fc1_b[wv*16 + h*4];
        float red[4];
#pragma unroll
        for (int r = 0; r < 4; ++r) {
            float v = (nw < 15) ? swish_(acc[r] + fb[r]) : 0.f;
            v += __shfl_xor(v, 1); v += __shfl_xor(v, 2);
            v += __shfl_xor(v, 4); v += __shfl_xor(v, 8);
            red[r] = v * (1.f / 15.f);
        }
        if (nw == 0) {
            f32x4 o4; o4[0] = red[0]; o4[1] = red[1]; o4[2] = red[2]; o4[3] = red[3];
            *(f32x4*)&hbar[be*64 + wv*16 + h*4] = o4;
        }
    }
}

/* ---------------- tail: fc2 + 3 cond-MLP blocks + head, 64 edges/block ---- */
__global__ __launch_bounds__(256) void tail_kernel(
    const float* __restrict__ latent,
    const float* __restrict__ fc2b_g,
    const float* __restrict__ mlf1b, const float* __restrict__ mlf2b,
    const float* __restrict__ mll1b, const float* __restrict__ mll2b,
    const float* __restrict__ em_w, const float* __restrict__ em_b,
    const float* __restrict__ ws, const float* __restrict__ hbar,
    float* __restrict__ out) {

    const int m0 = blockIdx.x * 64;
    const int tid = threadIdx.x, lane = tid & 63, wv = tid >> 6;
    const int row15 = lane & 15, hgp = lane >> 4;
    const int o_l = wv*16 + row15;                 /* this lane's output col */

    __shared__ __align__(16) unsigned short Hb[2][64*64];  /* bf16, swizzled */
    __shared__ float V[64][68];                            /* fp32 running vec */
    __shared__ float em_s[64];

    const unsigned short* bfp = (const unsigned short*)((const char*)ws + 8192);
    const short8* AFp = (const short8*)bfp;

    if (tid < 64) em_s[tid] = em_w[tid];

    /* load hbar -> Hb[0] */
    {
        const int e = tid >> 2, q = tid & 3;
        const f32x4* src = (const f32x4*)&hbar[(m0 + e)*64 + q*16];
#pragma unroll
        for (int v4 = 0; v4 < 4; ++v4) {
            f32x4 x = src[v4];
            const int o0 = q*16 + v4*4;
            const int slot = o0 >> 3, half = (o0 >> 2) & 1;
            u16x4 p; p[0]=f2bf(x[0]); p[1]=f2bf(x[1]); p[2]=f2bf(x[2]); p[3]=f2bf(x[3]);
            *(u16x4*)&Hb[0][e*64 + ((slot ^ (e & 7)) << 3) + half*4] = p;
        }
    }
    __syncthreads();

    /* latent A-frags, cached */
    short8 lf[4][2];
#pragma unroll
    for (int m = 0; m < 4; ++m)
#pragma unroll
        for (int kk = 0; kk < 2; ++kk) {
            const float* lp = &latent[(m0 + m*16 + row15)*64 + kk*32 + hgp*8];
            f32x4 a = *(const f32x4*)lp, c = *(const f32x4*)(lp + 4);
            short8 f;
            f[0]=f2bf(a[0]); f[1]=f2bf(a[1]); f[2]=f2bf(a[2]); f[3]=f2bf(a[3]);
            f[4]=f2bf(c[0]); f[5]=f2bf(c[1]); f[6]=f2bf(c[2]); f[7]=f2bf(c[3]);
            lf[m][kk] = f;
        }

#define RD_A(buf, m, kk) \
    (*(const short8*)&Hb[buf][(m*16 + row15)*64 + ((((kk)*4 + hgp) ^ ((m*16 + row15) & 7)) << 3)])
#define RD_FCP(g, kk)  AFp[24576 + (((g)*4 + wv)*2 + (kk))*64 + lane]
#define RD_CND(mb, nt, kk) AFp[18432 + (((mb)*16 + (nt))*2 + (kk))*64 + lane]
#define MFMA(a, b, c) __builtin_amdgcn_mfma_f32_16x16x32_bf16(a, b, c, 0, 0, 0)

    /* GEMM0: stage3 fc2 */
    f32x4 D[4];
#pragma unroll
    for (int m = 0; m < 4; ++m) D[m] = (f32x4){0.f,0.f,0.f,0.f};
#pragma unroll
    for (int kk = 0; kk < 2; ++kk) {
        short8 bfr = RD_FCP(0, kk);
#pragma unroll
        for (int m = 0; m < 4; ++m) D[m] = MFMA(RD_A(0, m, kk), bfr, D[m]);
    }
    {
        const float bias = fc2b_g[o_l];
#pragma unroll
        for (int m = 0; m < 4; ++m)
#pragma unroll
            for (int r = 0; r < 4; ++r) {
                const int ee = m*16 + hgp*4 + r;
                const float v = D[m][r] + bias;
                V[ee][o_l] = v;
                Hb[1][ee*64 + ((((o_l >> 3) ^ (ee & 7))) << 3) + (o_l & 7)] = f2bf(v);
            }
    }
    __syncthreads();

    /* 3 cond-MLP blocks: fc1 reads Hb[1], h1 -> Hb[0], fc2 reads Hb[0], v -> Hb[1] */
#pragma unroll 1
    for (int mb = 0; mb < 3; ++mb) {
        /* cond l1: gates (nt=wv) and shifts (nt=wv+4) */
        f32x4 G1[4], B1[4];
#pragma unroll
        for (int m = 0; m < 4; ++m) { G1[m] = (f32x4){0.f,0.f,0.f,0.f}; B1[m] = G1[m]; }
#pragma unroll
        for (int kk = 0; kk < 2; ++kk) {
            short8 bg = RD_CND(mb, wv,     kk);
            short8 bb = RD_CND(mb, wv + 4, kk);
#pragma unroll
            for (int m = 0; m < 4; ++m) {
                G1[m] = MFMA(lf[m][kk], bg, G1[m]);
                B1[m] = MFMA(lf[m][kk], bb, B1[m]);
            }
        }
        /* fc1 */
        f32x4 D1[4];
#pragma unroll
        for (int m = 0; m < 4; ++m) D1[m] = (f32x4){0.f,0.f,0.f,0.f};
#pragma unroll
        for (int kk = 0; kk < 2; ++kk) {
            short8 bfr = RD_FCP(1 + mb*2, kk);
#pragma unroll
            for (int m = 0; m < 4; ++m) D1[m] = MFMA(RD_A(1, m, kk), bfr, D1[m]);
        }
        {
            const float bfc  = mlf1b[mb*64 + o_l];
            const float bg1  = mll1b[mb*128 + o_l];
            const float bb1  = mll1b[mb*128 + 64 + o_l];
#pragma unroll
            for (int m = 0; m < 4; ++m)
#pragma unroll
                for (int r = 0; r < 4; ++r) {
                    const int ee = m*16 + hgp*4 + r;
                    const float h1 = swish_((G1[m][r] + bg1) * (D1[m][r] + bfc)
                                            + (B1[m][r] + bb1));
                    Hb[0][ee*64 + ((((o_l >> 3) ^ (ee & 7))) << 3) + (o_l & 7)] = f2bf(h1);
                }
        }
        __syncthreads();

        /* cond l2 */
        f32x4 G2[4], B2[4];
#pragma unroll
        for (int m = 0; m < 4; ++m) { G2[m] = (f32x4){0.f,0.f,0.f,0.f}; B2[m] = G2[m]; }
#pragma unroll
        for (int kk = 0; kk < 2; ++kk) {
            short8 bg = RD_CND(mb, wv + 8,  kk);
            short8 bb = RD_CND(mb, wv + 12, kk);
#pragma unroll
            for (int m = 0; m < 4; ++m) {
                G2[m] = MFMA(lf[m][kk], bg, G2[m]);
                B2[m] = MFMA(lf[m][kk], bb, B2[m]);
            }
        }
        /* fc2 */
        f32x4 D2[4];
#pragma unroll
        for (int m = 0; m < 4; ++m) D2[m] = (f32x4){0.f,0.f,0.f,0.f};
#pragma unroll
        for (int kk = 0; kk < 2; ++kk) {
            short8 bfr = RD_FCP(2 + mb*2, kk);
#pragma unroll
            for (int m = 0; m < 4; ++m) D2[m] = MFMA(RD_A(0, m, kk), bfr, D2[m]);
        }
        {
            const float bfc  = mlf2b[mb*64 + o_l];
            const float bg2  = mll2b[mb*128 + o_l];
            const float bb2  = mll2b[mb*128 + 64 + o_l];
#pragma unroll
            for (int m = 0; m < 4; ++m)
#pragma unroll
                for (int r = 0; r < 4; ++r) {
                    const int ee = m*16 + hgp*4 + r;
                    const float add = swish_((G2[m][r] + bg2) * (D2[m][r] + bfc)
                                             + (B2[m][r] + bb2));
                    const float vn = V[ee][o_l] + add;
                    V[ee][o_l] = vn;
                    Hb[1][ee*64 + ((((o_l >> 3) ^ (ee & 7))) << 3) + (o_l & 7)] = f2bf(vn);
                }
        }
        __syncthreads();
    }

    /* head */
    if (tid < 64) {
        const int ee = tid;
        float acc = em_b[0];
#pragma unroll 16
        for (int j = 0; j < 64; ++j) {
            const int o = (j + ee) & 63;
            acc += V[ee][o] * em_s[o];
        }
        out[m0 + ee] = acc;
    }
}

extern "C" void kernel_launch(void* const* d_in, const int* in_sizes, int n_in,
                              void* d_out, int out_size, void* d_ws, size_t ws_size,
                              hipStream_t stream) {
    const float* states   = (const float*)d_in[0];
    const float* latent   = (const float*)d_in[1];
    const float* cnnbf_w  = (const float*)d_in[2];
    const float* cnnbf_b  = (const float*)d_in[3];
    const float* rb1w     = (const float*)d_in[4];
    const float* rb1b     = (const float*)d_in[5];
    const float* rb2w     = (const float*)d_in[6];
    const float* rb2b     = (const float*)d_in[7];
    const float* rbl1w    = (const float*)d_in[8];
    const float* rbl1b    = (const float*)d_in[9];
    const float* rbl2w    = (const float*)d_in[10];
    const float* rbl2b    = (const float*)d_in[11];
    const float* fc1w     = (const float*)d_in[12];
    const float* fc1b     = (const float*)d_in[13];
    const float* fc2w     = (const float*)d_in[14];
    const float* fc2b     = (const float*)d_in[15];
    const float* mlf1w    = (const float*)d_in[16];
    const float* mlf1b    = (const float*)d_in[17];
    const float* mlf2w    = (const float*)d_in[18];
    const float* mlf2b    = (const float*)d_in[19];
    const float* mll1w    = (const float*)d_in[20];
    const float* mll1b    = (const float*)d_in[21];
    const float* mll2w    = (const float*)d_in[22];
    const float* mll2b    = (const float*)d_in[23];
    const float* em_w     = (const float*)d_in[24];
    const float* em_b     = (const float*)d_in[25];
    const int*   recv_idx = (const int*)d_in[26];
    const int*   send_idx = (const int*)d_in[27];
    float* ws  = (float*)d_ws;
    float* out = (float*)d_out;
    float* hbar = ws + HBAR_F32;

    prep_kernel<<<(N_PREP + 255) / 256, 256, 0, stream>>>(
        cnnbf_w, rb1w, rb2w, fc1w, fc2w, rbl1w, rbl2w, mll1w, mll2w, mlf1w, mlf2w, ws);

    mega_kernel<<<B_ * NE_, 256, 0, stream>>>(
        states, latent, cnnbf_b, rb1b, rb2b, rbl1b, rbl2b, fc1b,
        recv_idx, send_idx, ws, hbar);

    tail_kernel<<<(B_ * NE_) / 64, 256, 0, stream>>>(
        latent, fc2b, mlf1b, mlf2b, mll1b, mll2b, em_w, em_b, ws, hbar, out);
}

// Round 4
// 539.986 us; speedup vs baseline: 6.3245x; 1.1424x over previous
//
#include <hip/hip_runtime.h>

#define B_      2
#define NO_     96
#define T_      50
#define SD_     4
#define NE_     (NO_*(NO_-1))   /* 9120 */
#define F_      64
#define NW_     15

typedef __attribute__((ext_vector_type(8))) short  short8;   /* bf16x8 MFMA frag */
typedef __attribute__((ext_vector_type(4))) float  f32x4;
typedef __attribute__((ext_vector_type(4))) unsigned short u16x4;

/* ---- ws layout: bf16 pool (ushort) at byte 8192, element offsets ---- */
#define E_CONVA 0        /* [4 conv][4 m][10 kk][64][8]      = 81920 */
#define E_FC1A  81920    /* [4 m][16 kk][64][8] k=kt*64+f    = 32768 */
#define E_RBL   114688   /* rb cond frags [32 nt][2 kk][64][8]=32768 */
#define E_CONDP 147456   /* [3 mb][16 nt][2 kk][64][8]       = 49152 */
#define E_FCP   196608   /* [7 g][4 nt][2 kk][64][8]         = 28672 */
#define E_C0A   225280   /* conv0 A frags [4 m][64][8]       = 2048  */
#define N_BF16  227328
#define HBAR_F32 115712          /* float offset: (8192 + 2*N_BF16)/4 */

/* frag-index bases (element offset / 8) */
#define FI_FC1   10240
#define FI_RBL   14336
#define FI_CONDP 18432
#define FI_FCP   24576
#define FI_C0A   28160

#define MFMA(a, b, c) __builtin_amdgcn_mfma_f32_16x16x32_bf16(a, b, c, 0, 0, 0)

__device__ __forceinline__ float swish_(float v) { return v / (1.f + __expf(-v)); }

__device__ __forceinline__ unsigned short f2bf(float f) {
    unsigned u = __float_as_uint(f);
    u += 0x7FFFu + ((u >> 16) & 1u);
    return (unsigned short)(u >> 16);
}
__device__ __forceinline__ float bf2f(unsigned short u) {
    return __uint_as_float(((unsigned)u) << 16);
}

/* ------------------------------------------------------------------ */
__global__ void prep_kernel(const float* __restrict__ cnnbf_w,
                            const float* __restrict__ rb1w, const float* __restrict__ rb2w,
                            const float* __restrict__ fc1w, const float* __restrict__ fc2w,
                            const float* __restrict__ rbl1w, const float* __restrict__ rbl2w,
                            const float* __restrict__ mll1w, const float* __restrict__ mll2w,
                            const float* __restrict__ mlf1w, const float* __restrict__ mlf2w,
                            float* __restrict__ ws) {
    int e = blockIdx.x * blockDim.x + threadIdx.x;
    if (e >= N_BF16) return;
    unsigned short* bfp = (unsigned short*)((char*)ws + 8192);
    float v;
    if (e < E_FC1A) {                               /* conv A frags (k = tap*64+fi) */
        int r = e & 511, fid = e >> 9;
        int lane = r >> 3, j = r & 7;
        int kk = fid % 10, m = (fid / 10) & 3, c = fid / 40;
        int fo = m*16 + (lane & 15);
        int kidx = kk*32 + (lane >> 4)*8 + j;
        int k = kidx >> 6, fi = kidx & 63;
        int i = c >> 1;
        const float* src = (c & 1) ? rb2w : rb1w;
        v = src[((i*64 + fo)*64 + fi)*5 + k];
    } else if (e < E_RBL) {                         /* fc1 A frags, k = kt*64+f */
        int e2 = e - E_FC1A;
        int r = e2 & 511, fid = e2 >> 9;
        int lane = r >> 3, j = r & 7;
        int kk = fid & 15, m = fid >> 4;
        int fo = m*16 + (lane & 15);
        int k = kk*32 + (lane >> 4)*8 + j;
        int krow = (k & 63)*8 + (k >> 6);           /* original index = f*8 + kt */
        v = fc1w[fo*512 + krow];
    } else if (e < E_CONDP) {                       /* rb cond B frags */
        int e3 = e - E_RBL;
        int j = e3 & 7, lane = (e3 >> 3) & 63, fid = e3 >> 9;
        int kk = fid & 1, nt = fid >> 1;            /* nt in [0,32) */
        int rb = nt >> 4, which = (nt >> 3) & 1, ot = nt & 7;
        int o = ot*16 + (lane & 15);
        int k = kk*32 + (lane >> 4)*8 + j;
        const float* src = which ? rbl2w : rbl1w;
        v = src[(rb*128 + o)*64 + k];
    } else if (e < E_FCP) {                         /* mb cond B frags */
        int e4 = e - E_CONDP;
        int r = e4 & 511, fid = e4 >> 9;            /* fid = (mb*16+nt)*2+kk */
        int lane = r >> 3, j = r & 7;
        int kk = fid & 1, nt = (fid >> 1) & 15, mb = fid >> 5;
        int n = nt*16 + (lane & 15);
        int which = n >> 7, o = n & 127;
        int k = kk*32 + (lane >> 4)*8 + j;
        const float* src = which ? mll2w : mll1w;
        v = src[(mb*128 + o)*64 + k];
    } else if (e < E_C0A) {                         /* tail fc B frags */
        int e5 = e - E_FCP;
        int r = e5 & 511, fid = e5 >> 9;            /* fid = (g*4+nt)*2+kk */
        int lane = r >> 3, j = r & 7;
        int kk = fid & 1, nt = (fid >> 1) & 3, g = fid >> 3;
        int o = nt*16 + (lane & 15);
        int k = kk*32 + (lane >> 4)*8 + j;
        if (g == 0) v = fc2w[o*64 + k];
        else {
            int mb = (g - 1) >> 1;
            const float* src = ((g - 1) & 1) ? mlf2w : mlf1w;
            v = src[(mb*64 + o)*64 + k];
        }
    } else {                                        /* conv0 A frags (K=24 pad 32) */
        int e6 = e - E_C0A;
        int j = e6 & 7, lane = (e6 >> 3) & 63, m = e6 >> 9;
        int fo = m*16 + (lane & 15);
        int k = (lane >> 4)*8 + j;
        int tap = k >> 3, fi = k & 7;
        v = (tap < 3) ? cnnbf_w[(fo*8 + fi)*3 + tap] : 0.f;
    }
    bfp[e] = f2bf(v);
}

/* ---------------- conv 64->64 k=5 via MFMA, wave=(mi,ni) 2x2 -------
   xT/hT: bf16 swizzled [54 rows][64 fi], slot' = slot ^ (row&7).
   wave covers M-tiles {2mi,2mi+1}, N-tiles: ni=0 -> t0 {0,16},
   ni=1 -> t0 {32,34} (tile 34 cols<14 are duplicates, skipped). */
template<bool ISCONV2>
__device__ __forceinline__ void convpass2(const short8* __restrict__ AF, int fb,
                                          const unsigned short* __restrict__ Bsrc,
                                          unsigned short* __restrict__ Dst,
                                          const float* __restrict__ cb,
                                          const float* __restrict__ gv,
                                          const float* __restrict__ bv,
                                          int lane, int row0, int g0, int mi, int ni) {
    const int t0a = ni * 32;
    f32x4 acc00 = {0.f,0.f,0.f,0.f}, acc01 = acc00, acc10 = acc00, acc11 = acc00;
#pragma unroll
    for (int kk = 0; kk < 10; ++kk) {
        short8 a0 = AF[fb + ((mi*2 + 0)*10 + kk)*64 + lane];
        short8 a1 = AF[fb + ((mi*2 + 1)*10 + kk)*64 + lane];
        const int c  = ((kk & 1) << 2) + g0;
        const int sa = t0a + row0 + (kk >> 1);
        const int ia = sa*64 + ((c ^ (sa & 7)) << 3);
        short8 b0 = *(const short8*)&Bsrc[ia];
        short8 b1;
        if (ni == 0) b1 = *(const short8*)&Bsrc[ia + 1024];
        else { const int sb2 = sa + 2; b1 = *(const short8*)&Bsrc[sb2*64 + ((c ^ (sb2 & 7)) << 3)]; }
        acc00 = MFMA(a0, b0, acc00); acc01 = MFMA(a0, b1, acc01);
        acc10 = MFMA(a1, b0, acc10); acc11 = MFMA(a1, b1, acc11);
    }
#pragma unroll
    for (int a = 0; a < 2; ++a) {
        const int fo0 = (mi*2 + a)*16 + g0*4;
        const f32x4 cb4 = *(const f32x4*)&cb[fo0];
        const f32x4 g4  = *(const f32x4*)&gv[fo0];
        const f32x4 b4  = *(const f32x4*)&bv[fo0];
#pragma unroll
        for (int n = 0; n < 2; ++n) {
            if (ni == 1 && n == 1 && row0 < 14) continue;
            const int t = ((n == 0) ? t0a : (ni == 0 ? 16 : 34)) + row0;
            const f32x4 A = (a == 0) ? ((n == 0) ? acc00 : acc01)
                                     : ((n == 0) ? acc10 : acc11);
            float s0 = swish_(g4[0]*(A[0] + cb4[0]) + b4[0]);
            float s1 = swish_(g4[1]*(A[1] + cb4[1]) + b4[1]);
            float s2 = swish_(g4[2]*(A[2] + cb4[2]) + b4[2]);
            float s3 = swish_(g4[3]*(A[3] + cb4[3]) + b4[3]);
            const int rw = t + 2;
            const int dix = rw*64 + ((((fo0 >> 3) ^ (rw & 7))) << 3) + (fo0 & 7);
            if (ISCONV2) {
                u16x4 old = *(u16x4*)&Dst[dix];
                s0 += bf2f(old[0]); s1 += bf2f(old[1]);
                s2 += bf2f(old[2]); s3 += bf2f(old[3]);
            }
            u16x4 q; q[0] = f2bf(s0); q[1] = f2bf(s1); q[2] = f2bf(s2); q[3] = f2bf(s3);
            *(u16x4*)&Dst[dix] = q;
        }
    }
}

/* ------------------------------------------------------------------ */
__global__ __launch_bounds__(256) void mega_kernel(
    const float* __restrict__ states, const float* __restrict__ latent,
    const float* __restrict__ cnnbf_b,
    const float* __restrict__ rb_conv1_b, const float* __restrict__ rb_conv2_b,
    const float* __restrict__ rb_lfc1_b, const float* __restrict__ rb_lfc2_b,
    const float* __restrict__ mlp1_fc1_b,
    const int* __restrict__ recv_idx, const int* __restrict__ send_idx,
    const float* __restrict__ ws, float* __restrict__ hbar) {

    const int be = blockIdx.x;
    const int b  = be / NE_;
    const int e  = be % NE_;
    const int tid  = threadIdx.x;
    const int lane = tid & 63;
    const int wv   = tid >> 6;
    const int row0 = lane & 15, g0 = lane >> 4;
    const int mi = wv & 1, ni = wv >> 1;

    __shared__ __align__(16) unsigned short xT[54*64];   /* bf16 trunk, swizzled */
    __shared__ __align__(16) unsigned short hT[54*64];
    __shared__ __align__(16) unsigned short x0T[54*8];   /* bf16 input, [row][fi] */
    __shared__ __align__(16) unsigned short lat_bf[64];
    __shared__ __align__(16) float cond_s[512];          /* [rb][g1|b1|g2|b2] */

    const unsigned short* bfp = (const unsigned short*)((const char*)ws + 8192);
    const short8* AF = (const short8*)bfp;

    /* ---- stage 0: zero pads, gather ---- */
    {
        int r = tid >> 6; int row = (r < 2) ? r : 50 + r;
        xT[row*64 + (tid & 63)] = 0;
        hT[row*64 + (tid & 63)] = 0;
        if (tid < 4) {                                   /* x0T rows 0,51,52,53 */
            const int rz = (tid == 0) ? 0 : 50 + tid;
            short8 z = {0,0,0,0,0,0,0,0};
            *(short8*)&x0T[rz*8] = z;
        }
    }
    const int recv = recv_idx[e];
    const int send = send_idx[e];
    for (int i = tid; i < 8 * T_; i += 256) {
        const int c = i / T_, t = i % T_;
        const float v = (c < 4)
            ? states[((b*NO_ + recv)*T_ + t)*SD_ + c]
            : states[((b*NO_ + send)*T_ + t)*SD_ + (c - 4)];
        x0T[(t + 1)*8 + c] = f2bf(v);
    }
    if (tid < 64) lat_bf[tid] = f2bf(latent[(b*NE_ + e)*64 + tid]);
    __syncthreads();

    /* ---- stage 1: conv0 via MFMA + both rb conds via MFMA ---- */
    {
        /* conv0: B[k=tap*8+fi][col=t] = x0T[t+tap][fi]; lane's tap = g0 */
        const int t0a = ni * 32;
        const int sa = t0a + row0 + g0;
        short8 b0 = *(const short8*)&x0T[sa * 8];
        const int sb = (ni == 0) ? (sa + 16) : (sa + 2);
        short8 b1 = *(const short8*)&x0T[sb * 8];
        short8 a0 = AF[FI_C0A + (mi*2 + 0)*64 + lane];
        short8 a1 = AF[FI_C0A + (mi*2 + 1)*64 + lane];
        f32x4 z4 = {0.f,0.f,0.f,0.f};
        f32x4 c00 = MFMA(a0, b0, z4), c01 = MFMA(a0, b1, z4);
        f32x4 c10 = MFMA(a1, b0, z4), c11 = MFMA(a1, b1, z4);
#pragma unroll
        for (int a = 0; a < 2; ++a) {
            const int fo0 = (mi*2 + a)*16 + g0*4;
            const f32x4 cb4 = *(const f32x4*)&cnnbf_b[fo0];
#pragma unroll
            for (int n = 0; n < 2; ++n) {
                if (ni == 1 && n == 1 && row0 < 14) continue;
                const int t = ((n == 0) ? t0a : (ni == 0 ? 16 : 34)) + row0;
                const f32x4 A = (a == 0) ? ((n == 0) ? c00 : c01)
                                         : ((n == 0) ? c10 : c11);
                const int rw = t + 2;
                const int dix = rw*64 + ((((fo0 >> 3) ^ (rw & 7))) << 3) + (fo0 & 7);
                u16x4 q;
                q[0] = f2bf(swish_(A[0] + cb4[0]));
                q[1] = f2bf(swish_(A[1] + cb4[1]));
                q[2] = f2bf(swish_(A[2] + cb4[2]));
                q[3] = f2bf(swish_(A[3] + cb4[3]));
                *(u16x4*)&xT[dix] = q;
            }
        }
        /* rb conds: wave = (rb, which); lat broadcast A (all rows equal) */
        short8 la0 = *(const short8*)&lat_bf[g0 * 8];
        short8 la1 = *(const short8*)&lat_bf[32 + g0 * 8];
        const int rbq = wv >> 1, whq = wv & 1;
        const float* cbias = (whq ? rb_lfc2_b : rb_lfc1_b) + rbq*128;
        float* cdst = cond_s + rbq*256 + whq*128;
#pragma unroll
        for (int q8 = 0; q8 < 8; ++q8) {
            f32x4 d = z4;
            d = MFMA(la0, AF[FI_RBL + ((wv*8 + q8)*2 + 0)*64 + lane], d);
            d = MFMA(la1, AF[FI_RBL + ((wv*8 + q8)*2 + 1)*64 + lane], d);
            if (g0 == 0) {
                const int o = q8*16 + row0;
                cdst[o] = d[0] + cbias[o];
            }
        }
    }
    __syncthreads();

    /* ---- stage 2: residual blocks ---- */
#pragma unroll 1
    for (int rb = 0; rb < 2; ++rb) {
        const float* cs = cond_s + rb*256;
        convpass2<false>(AF, (rb*2 + 0)*2560, xT, hT,
                         rb_conv1_b + rb*64, cs, cs + 64, lane, row0, g0, mi, ni);
        __syncthreads();
        convpass2<true>(AF, (rb*2 + 1)*2560, hT, xT,
                        rb_conv2_b + rb*64, cs + 128, cs + 192, lane, row0, g0, mi, ni);
        __syncthreads();
    }

    /* ---- stage 3: windowed MLP fc1 (k = kt*64+f) + folded mean ---- */
    {
        const int h = g0, nw = row0;
        f32x4 acc = {0.f,0.f,0.f,0.f};
        const int nwe = (nw < 15) ? nw : 14;
        const int nwrow = 3*nwe + 2;
#pragma unroll
        for (int kk = 0; kk < 16; ++kk) {
            short8 a = AF[FI_FC1 + (wv*16 + kk)*64 + lane];
            const int row = nwrow + (kk >> 1);
            const int g   = ((kk & 1) << 2) + h;
            short8 bfr = *(const short8*)&xT[row*64 + ((g ^ (row & 7)) << 3)];
            acc = MFMA(a, bfr, acc);
        }
        const f32x4 fb = *(const f32x4*)&mlp1_fc1_b[wv*16 + h*4];
        float red[4];
#pragma unroll
        for (int r = 0; r < 4; ++r) {
            float v = (nw < 15) ? swish_(acc[r] + fb[r]) : 0.f;
            v += __shfl_xor(v, 1); v += __shfl_xor(v, 2);
            v += __shfl_xor(v, 4); v += __shfl_xor(v, 8);
            red[r] = v * (1.f / 15.f);
        }
        if (nw == 0) {
            f32x4 o4; o4[0] = red[0]; o4[1] = red[1]; o4[2] = red[2]; o4[3] = red[3];
            *(f32x4*)&hbar[be*64 + wv*16 + h*4] = o4;
        }
    }
}

/* ---------------- tail: fc2 + 3 cond-MLP blocks + head, 64 edges/block ---- */
__global__ __launch_bounds__(256) void tail_kernel(
    const float* __restrict__ latent,
    const float* __restrict__ fc2b_g,
    const float* __restrict__ mlf1b, const float* __restrict__ mlf2b,
    const float* __restrict__ mll1b, const float* __restrict__ mll2b,
    const float* __restrict__ em_w, const float* __restrict__ em_b,
    const float* __restrict__ ws, const float* __restrict__ hbar,
    float* __restrict__ out) {

    const int m0 = blockIdx.x * 64;
    const int tid = threadIdx.x, lane = tid & 63, wv = tid >> 6;
    const int row15 = lane & 15, hgp = lane >> 4;
    const int o_l = wv*16 + row15;                 /* this lane's output col */

    __shared__ __align__(16) unsigned short Hb[2][64*64];  /* bf16, swizzled */
    __shared__ float V[64][68];                            /* fp32 running vec */
    __shared__ float em_s[64];

    const unsigned short* bfp = (const unsigned short*)((const char*)ws + 8192);
    const short8* AFp = (const short8*)bfp;

    if (tid < 64) em_s[tid] = em_w[tid];

    /* load hbar -> Hb[0] */
    {
        const int e = tid >> 2, q = tid & 3;
        const f32x4* src = (const f32x4*)&hbar[(m0 + e)*64 + q*16];
#pragma unroll
        for (int v4 = 0; v4 < 4; ++v4) {
            f32x4 x = src[v4];
            const int o0 = q*16 + v4*4;
            const int slot = o0 >> 3, half = (o0 >> 2) & 1;
            u16x4 p; p[0]=f2bf(x[0]); p[1]=f2bf(x[1]); p[2]=f2bf(x[2]); p[3]=f2bf(x[3]);
            *(u16x4*)&Hb[0][e*64 + ((slot ^ (e & 7)) << 3) + half*4] = p;
        }
    }
    __syncthreads();

    /* latent A-frags, cached */
    short8 lf[4][2];
#pragma unroll
    for (int m = 0; m < 4; ++m)
#pragma unroll
        for (int kk = 0; kk < 2; ++kk) {
            const float* lp = &latent[(m0 + m*16 + row15)*64 + kk*32 + hgp*8];
            f32x4 a = *(const f32x4*)lp, c = *(const f32x4*)(lp + 4);
            short8 f;
            f[0]=f2bf(a[0]); f[1]=f2bf(a[1]); f[2]=f2bf(a[2]); f[3]=f2bf(a[3]);
            f[4]=f2bf(c[0]); f[5]=f2bf(c[1]); f[6]=f2bf(c[2]); f[7]=f2bf(c[3]);
            lf[m][kk] = f;
        }

#define RD_A(buf, m, kk) \
    (*(const short8*)&Hb[buf][(m*16 + row15)*64 + ((((kk)*4 + hgp) ^ ((m*16 + row15) & 7)) << 3)])
#define RD_FCP(g, kk)  AFp[FI_FCP + (((g)*4 + wv)*2 + (kk))*64 + lane]
#define RD_CND(mb, nt, kk) AFp[FI_CONDP + (((mb)*16 + (nt))*2 + (kk))*64 + lane]

    /* GEMM0: stage3 fc2 */
    f32x4 D[4];
#pragma unroll
    for (int m = 0; m < 4; ++m) D[m] = (f32x4){0.f,0.f,0.f,0.f};
#pragma unroll
    for (int kk = 0; kk < 2; ++kk) {
        short8 bfr = RD_FCP(0, kk);
#pragma unroll
        for (int m = 0; m < 4; ++m) D[m] = MFMA(RD_A(0, m, kk), bfr, D[m]);
    }
    {
        const float bias = fc2b_g[o_l];
#pragma unroll
        for (int m = 0; m < 4; ++m)
#pragma unroll
            for (int r = 0; r < 4; ++r) {
                const int ee = m*16 + hgp*4 + r;
                const float v = D[m][r] + bias;
                V[ee][o_l] = v;
                Hb[1][ee*64 + ((((o_l >> 3) ^ (ee & 7))) << 3) + (o_l & 7)] = f2bf(v);
            }
    }
    __syncthreads();

    /* 3 cond-MLP blocks */
#pragma unroll 1
    for (int mb = 0; mb < 3; ++mb) {
        f32x4 G1[4], B1[4];
#pragma unroll
        for (int m = 0; m < 4; ++m) { G1[m] = (f32x4){0.f,0.f,0.f,0.f}; B1[m] = G1[m]; }
#pragma unroll
        for (int kk = 0; kk < 2; ++kk) {
            short8 bg = RD_CND(mb, wv,     kk);
            short8 bb = RD_CND(mb, wv + 4, kk);
#pragma unroll
            for (int m = 0; m < 4; ++m) {
                G1[m] = MFMA(lf[m][kk], bg, G1[m]);
                B1[m] = MFMA(lf[m][kk], bb, B1[m]);
            }
        }
        f32x4 D1[4];
#pragma unroll
        for (int m = 0; m < 4; ++m) D1[m] = (f32x4){0.f,0.f,0.f,0.f};
#pragma unroll
        for (int kk = 0; kk < 2; ++kk) {
            short8 bfr = RD_FCP(1 + mb*2, kk);
#pragma unroll
            for (int m = 0; m < 4; ++m) D1[m] = MFMA(RD_A(1, m, kk), bfr, D1[m]);
        }
        {
            const float bfc  = mlf1b[mb*64 + o_l];
            const float bg1  = mll1b[mb*128 + o_l];
            const float bb1  = mll1b[mb*128 + 64 + o_l];
#pragma unroll
            for (int m = 0; m < 4; ++m)
#pragma unroll
                for (int r = 0; r < 4; ++r) {
                    const int ee = m*16 + hgp*4 + r;
                    const float h1 = swish_((G1[m][r] + bg1) * (D1[m][r] + bfc)
                                            + (B1[m][r] + bb1));
                    Hb[0][ee*64 + ((((o_l >> 3) ^ (ee & 7))) << 3) + (o_l & 7)] = f2bf(h1);
                }
        }
        __syncthreads();

        f32x4 G2[4], B2[4];
#pragma unroll
        for (int m = 0; m < 4; ++m) { G2[m] = (f32x4){0.f,0.f,0.f,0.f}; B2[m] = G2[m]; }
#pragma unroll
        for (int kk = 0; kk < 2; ++kk) {
            short8 bg = RD_CND(mb, wv + 8,  kk);
            short8 bb = RD_CND(mb, wv + 12, kk);
#pragma unroll
            for (int m = 0; m < 4; ++m) {
                G2[m] = MFMA(lf[m][kk], bg, G2[m]);
                B2[m] = MFMA(lf[m][kk], bb, B2[m]);
            }
        }
        f32x4 D2[4];
#pragma unroll
        for (int m = 0; m < 4; ++m) D2[m] = (f32x4){0.f,0.f,0.f,0.f};
#pragma unroll
        for (int kk = 0; kk < 2; ++kk) {
            short8 bfr = RD_FCP(2 + mb*2, kk);
#pragma unroll
            for (int m = 0; m < 4; ++m) D2[m] = MFMA(RD_A(0, m, kk), bfr, D2[m]);
        }
        {
            const float bfc  = mlf2b[mb*64 + o_l];
            const float bg2  = mll2b[mb*128 + o_l];
            const float bb2  = mll2b[mb*128 + 64 + o_l];
#pragma unroll
            for (int m = 0; m < 4; ++m)
#pragma unroll
                for (int r = 0; r < 4; ++r) {
                    const int ee = m*16 + hgp*4 + r;
                    const float add = swish_((G2[m][r] + bg2) * (D2[m][r] + bfc)
                                             + (B2[m][r] + bb2));
                    const float vn = V[ee][o_l] + add;
                    V[ee][o_l] = vn;
                    Hb[1][ee*64 + ((((o_l >> 3) ^ (ee & 7))) << 3) + (o_l & 7)] = f2bf(vn);
                }
        }
        __syncthreads();
    }

    /* head */
    if (tid < 64) {
        const int ee = tid;
        float acc = em_b[0];
#pragma unroll 16
        for (int j = 0; j < 64; ++j) {
            const int o = (j + ee) & 63;
            acc += V[ee][o] * em_s[o];
        }
        out[m0 + ee] = acc;
    }
}

extern "C" void kernel_launch(void* const* d_in, const int* in_sizes, int n_in,
                              void* d_out, int out_size, void* d_ws, size_t ws_size,
                              hipStream_t stream) {
    const float* states   = (const float*)d_in[0];
    const float* latent   = (const float*)d_in[1];
    const float* cnnbf_w  = (const float*)d_in[2];
    const float* cnnbf_b  = (const float*)d_in[3];
    const float* rb1w     = (const float*)d_in[4];
    const float* rb1b     = (const float*)d_in[5];
    const float* rb2w     = (const float*)d_in[6];
    const float* rb2b     = (const float*)d_in[7];
    const float* rbl1w    = (const float*)d_in[8];
    const float* rbl1b    = (const float*)d_in[9];
    const float* rbl2w    = (const float*)d_in[10];
    const float* rbl2b    = (const float*)d_in[11];
    const float* fc1w     = (const float*)d_in[12];
    const float* fc1b     = (const float*)d_in[13];
    const float* fc2w     = (const float*)d_in[14];
    const float* fc2b     = (const float*)d_in[15];
    const float* mlf1w    = (const float*)d_in[16];
    const float* mlf1b    = (const float*)d_in[17];
    const float* mlf2w    = (const float*)d_in[18];
    const float* mlf2b    = (const float*)d_in[19];
    const float* mll1w    = (const float*)d_in[20];
    const float* mll1b    = (const float*)d_in[21];
    const float* mll2w    = (const float*)d_in[22];
    const float* mll2b    = (const float*)d_in[23];
    const float* em_w     = (const float*)d_in[24];
    const float* em_b     = (const float*)d_in[25];
    const int*   recv_idx = (const int*)d_in[26];
    const int*   send_idx = (const int*)d_in[27];
    float* ws  = (float*)d_ws;
    float* out = (float*)d_out;
    float* hbar = ws + HBAR_F32;

    prep_kernel<<<(N_BF16 + 255) / 256, 256, 0, stream>>>(
        cnnbf_w, rb1w, rb2w, fc1w, fc2w, rbl1w, rbl2w, mll1w, mll2w, mlf1w, mlf2w, ws);

    mega_kernel<<<B_ * NE_, 256, 0, stream>>>(
        states, latent, cnnbf_b, rb1b, rb2b, rbl1b, rbl2b, fc1b,
        recv_idx, send_idx, ws, hbar);

    tail_kernel<<<(B_ * NE_) / 64, 256, 0, stream>>>(
        latent, fc2b, mlf1b, mlf2b, mll1b, mll2b, em_w, em_b, ws, hbar, out);
}

// Round 5
// 367.465 us; speedup vs baseline: 9.2938x; 1.4695x over previous
//
#include <hip/hip_runtime.h>

#define B_      2
#define NO_     96
#define T_      50
#define SD_     4
#define NE_     (NO_*(NO_-1))   /* 9120 */
#define F_      64
#define NW_     15

typedef __attribute__((ext_vector_type(8))) short  short8;   /* bf16x8 MFMA frag */
typedef __attribute__((ext_vector_type(4))) float  f32x4;
typedef __attribute__((ext_vector_type(4))) unsigned short u16x4;

/* ---- ws layout: bf16 pool (ushort) at byte 8192, element offsets ---- */
#define E_CONVA 0        /* [4 conv][4 m][10 kk][64][8]      = 81920 */
#define E_FC1A  81920    /* [4 m][16 kk][64][8] k=kt*64+f    = 32768 */
#define E_RBL   114688   /* rb cond frags [32 nt][2 kk][64][8]=32768 */
#define E_CONDP 147456   /* [3 mb][16 nt][2 kk][64][8]       = 49152 */
#define E_FCP   196608   /* [7 g][4 nt][2 kk][64][8]         = 28672 */
#define E_C0A   225280   /* conv0 A frags [4 m][64][8]       = 2048  */
#define N_BF16  227328
#define HBAR_F32 115712          /* float offset: (8192 + 2*N_BF16)/4 */

/* frag-index bases (element offset / 8) */
#define FI_FC1   10240
#define FI_RBL   14336
#define FI_CONDP 18432
#define FI_FCP   24576
#define FI_C0A   28160

#define XSTRIDE  3456            /* 54*64 ushorts per edge buffer */

#define MFMA(a, b, c) __builtin_amdgcn_mfma_f32_16x16x32_bf16(a, b, c, 0, 0, 0)

__device__ __forceinline__ float swish_(float v) { return v / (1.f + __expf(-v)); }

__device__ __forceinline__ unsigned short f2bf(float f) {
    unsigned u = __float_as_uint(f);
    u += 0x7FFFu + ((u >> 16) & 1u);
    return (unsigned short)(u >> 16);
}
__device__ __forceinline__ float bf2f(unsigned short u) {
    return __uint_as_float(((unsigned)u) << 16);
}

/* ------------------------------------------------------------------ */
__global__ void prep_kernel(const float* __restrict__ cnnbf_w,
                            const float* __restrict__ rb1w, const float* __restrict__ rb2w,
                            const float* __restrict__ fc1w, const float* __restrict__ fc2w,
                            const float* __restrict__ rbl1w, const float* __restrict__ rbl2w,
                            const float* __restrict__ mll1w, const float* __restrict__ mll2w,
                            const float* __restrict__ mlf1w, const float* __restrict__ mlf2w,
                            float* __restrict__ ws) {
    int e = blockIdx.x * blockDim.x + threadIdx.x;
    if (e >= N_BF16) return;
    unsigned short* bfp = (unsigned short*)((char*)ws + 8192);
    float v;
    if (e < E_FC1A) {                               /* conv A frags (k = tap*64+fi) */
        int r = e & 511, fid = e >> 9;
        int lane = r >> 3, j = r & 7;
        int kk = fid % 10, m = (fid / 10) & 3, c = fid / 40;
        int fo = m*16 + (lane & 15);
        int kidx = kk*32 + (lane >> 4)*8 + j;
        int k = kidx >> 6, fi = kidx & 63;
        int i = c >> 1;
        const float* src = (c & 1) ? rb2w : rb1w;
        v = src[((i*64 + fo)*64 + fi)*5 + k];
    } else if (e < E_RBL) {                         /* fc1 A frags, k = kt*64+f */
        int e2 = e - E_FC1A;
        int r = e2 & 511, fid = e2 >> 9;
        int lane = r >> 3, j = r & 7;
        int kk = fid & 15, m = fid >> 4;
        int fo = m*16 + (lane & 15);
        int k = kk*32 + (lane >> 4)*8 + j;
        int krow = (k & 63)*8 + (k >> 6);           /* original index = f*8 + kt */
        v = fc1w[fo*512 + krow];
    } else if (e < E_CONDP) {                       /* rb cond B frags */
        int e3 = e - E_RBL;
        int j = e3 & 7, lane = (e3 >> 3) & 63, fid = e3 >> 9;
        int kk = fid & 1, nt = fid >> 1;            /* nt in [0,32) */
        int rb = nt >> 4, which = (nt >> 3) & 1, ot = nt & 7;
        int o = ot*16 + (lane & 15);
        int k = kk*32 + (lane >> 4)*8 + j;
        const float* src = which ? rbl2w : rbl1w;
        v = src[(rb*128 + o)*64 + k];
    } else if (e < E_FCP) {                         /* mb cond B frags */
        int e4 = e - E_CONDP;
        int r = e4 & 511, fid = e4 >> 9;            /* fid = (mb*16+nt)*2+kk */
        int lane = r >> 3, j = r & 7;
        int kk = fid & 1, nt = (fid >> 1) & 15, mb = fid >> 5;
        int n = nt*16 + (lane & 15);
        int which = n >> 7, o = n & 127;
        int k = kk*32 + (lane >> 4)*8 + j;
        const float* src = which ? mll2w : mll1w;
        v = src[(mb*128 + o)*64 + k];
    } else if (e < E_C0A) {                         /* tail fc B frags */
        int e5 = e - E_FCP;
        int r = e5 & 511, fid = e5 >> 9;            /* fid = (g*4+nt)*2+kk */
        int lane = r >> 3, j = r & 7;
        int kk = fid & 1, nt = (fid >> 1) & 3, g = fid >> 3;
        int o = nt*16 + (lane & 15);
        int k = kk*32 + (lane >> 4)*8 + j;
        if (g == 0) v = fc2w[o*64 + k];
        else {
            int mb = (g - 1) >> 1;
            const float* src = ((g - 1) & 1) ? mlf2w : mlf1w;
            v = src[(mb*64 + o)*64 + k];
        }
    } else {                                        /* conv0 A frags (K=24 pad 32) */
        int e6 = e - E_C0A;
        int j = e6 & 7, lane = (e6 >> 3) & 63, m = e6 >> 9;
        int fo = m*16 + (lane & 15);
        int k = (lane >> 4)*8 + j;
        int tap = k >> 3, fi = k & 7;
        v = (tap < 3) ? cnnbf_w[(fo*8 + fi)*3 + tap] : 0.f;
    }
    bfp[e] = f2bf(v);
}

/* ---------------- conv 64->64 k=5 via MFMA, wave=(mi,ni), 2 edges --
   A-fragments loaded ONCE per wave and reused for both edges.       */
template<bool ISCONV2>
__device__ __forceinline__ void convpass2e(const short8* __restrict__ AF, int fb,
        const unsigned short* __restrict__ Bb, unsigned short* __restrict__ Db,
        const float* __restrict__ cb,
        const float* __restrict__ gv0, const float* __restrict__ bv0,
        const float* __restrict__ gv1, const float* __restrict__ bv1,
        int lane, int row0, int g0, int mi, int ni) {
    const int t0a = ni * 32;
    f32x4 acc[2][4];
#pragma unroll
    for (int ed = 0; ed < 2; ++ed)
#pragma unroll
        for (int q = 0; q < 4; ++q) acc[ed][q] = (f32x4){0.f,0.f,0.f,0.f};
#pragma unroll
    for (int kk = 0; kk < 10; ++kk) {
        short8 a0 = AF[fb + ((mi*2 + 0)*10 + kk)*64 + lane];
        short8 a1 = AF[fb + ((mi*2 + 1)*10 + kk)*64 + lane];
        const int c  = ((kk & 1) << 2) + g0;
        const int sa = t0a + row0 + (kk >> 1);
        const int ia = sa*64 + ((c ^ (sa & 7)) << 3);
        int ib;
        if (ni == 0) ib = ia + 1024;
        else { const int sb2 = sa + 2; ib = sb2*64 + ((c ^ (sb2 & 7)) << 3); }
#pragma unroll
        for (int ed = 0; ed < 2; ++ed) {
            const unsigned short* Bs = Bb + ed*XSTRIDE;
            short8 b0 = *(const short8*)&Bs[ia];
            short8 b1 = *(const short8*)&Bs[ib];
            acc[ed][0] = MFMA(a0, b0, acc[ed][0]);
            acc[ed][1] = MFMA(a0, b1, acc[ed][1]);
            acc[ed][2] = MFMA(a1, b0, acc[ed][2]);
            acc[ed][3] = MFMA(a1, b1, acc[ed][3]);
        }
    }
#pragma unroll
    for (int ed = 0; ed < 2; ++ed) {
        const float* gv = ed ? gv1 : gv0;
        const float* bv = ed ? bv1 : bv0;
        unsigned short* Dst = Db + ed*XSTRIDE;
#pragma unroll
        for (int a = 0; a < 2; ++a) {
            const int fo0 = (mi*2 + a)*16 + g0*4;
            const f32x4 cb4 = *(const f32x4*)&cb[fo0];
            const f32x4 g4  = *(const f32x4*)&gv[fo0];
            const f32x4 b4  = *(const f32x4*)&bv[fo0];
#pragma unroll
            for (int n = 0; n < 2; ++n) {
                if (ni == 1 && n == 1 && row0 < 14) continue;
                const int t = ((n == 0) ? t0a : (ni == 0 ? 16 : 34)) + row0;
                const f32x4 A = acc[ed][a*2 + n];
                float s0 = swish_(g4[0]*(A[0] + cb4[0]) + b4[0]);
                float s1 = swish_(g4[1]*(A[1] + cb4[1]) + b4[1]);
                float s2 = swish_(g4[2]*(A[2] + cb4[2]) + b4[2]);
                float s3 = swish_(g4[3]*(A[3] + cb4[3]) + b4[3]);
                const int rw = t + 2;
                const int dix = rw*64 + ((((fo0 >> 3) ^ (rw & 7))) << 3) + (fo0 & 7);
                if (ISCONV2) {
                    u16x4 old = *(u16x4*)&Dst[dix];
                    s0 += bf2f(old[0]); s1 += bf2f(old[1]);
                    s2 += bf2f(old[2]); s3 += bf2f(old[3]);
                }
                u16x4 q; q[0] = f2bf(s0); q[1] = f2bf(s1); q[2] = f2bf(s2); q[3] = f2bf(s3);
                *(u16x4*)&Dst[dix] = q;
            }
        }
    }
}

/* ------------------------------------------------------------------ */
__global__ __launch_bounds__(256, 4) void mega_kernel(
    const float* __restrict__ states, const float* __restrict__ latent,
    const float* __restrict__ cnnbf_b,
    const float* __restrict__ rb_conv1_b, const float* __restrict__ rb_conv2_b,
    const float* __restrict__ rb_lfc1_b, const float* __restrict__ rb_lfc2_b,
    const float* __restrict__ mlp1_fc1_b,
    const int* __restrict__ recv_idx, const int* __restrict__ send_idx,
    const float* __restrict__ ws, float* __restrict__ hbar) {

    const int ge0 = blockIdx.x * 2;                /* two edges per block */
    const int tid  = threadIdx.x;
    const int lane = tid & 63;
    const int wv   = tid >> 6;
    const int row0 = lane & 15, g0 = lane >> 4;
    const int mi = wv & 1, ni = wv >> 1;

    __shared__ __align__(16) unsigned short xTb[2*54*64];  /* bf16 trunk, swizzled */
    __shared__ __align__(16) unsigned short hTb[2*54*64];
    __shared__ __align__(16) unsigned short x0Tb[2*54*8];  /* bf16 input, [row][fi] */
    __shared__ __align__(16) unsigned short lat_bfb[2*64];
    __shared__ __align__(16) float cond_sb[2*512];

    const unsigned short* bfp = (const unsigned short*)((const char*)ws + 8192);
    const short8* AF = (const short8*)bfp;

    /* ---- stage 0: zero pads, gather both edges ---- */
    for (int z = tid; z < 512; z += 256) {
        const int edz = z >> 8, rr = (z >> 6) & 3, cc = z & 63;
        const int row = (rr < 2) ? rr : 50 + rr;
        xTb[edz*XSTRIDE + row*64 + cc] = 0;
        hTb[edz*XSTRIDE + row*64 + cc] = 0;
    }
    if (tid < 8) {
        const int edz = tid >> 2, q = tid & 3;
        const int rz = (q == 0) ? 0 : 50 + q;
        short8 zz = {0,0,0,0,0,0,0,0};
        *(short8*)&x0Tb[edz*432 + rz*8] = zz;
    }
    const int b0_ = ge0 / NE_,       e0_ = ge0 % NE_;
    const int b1_ = (ge0+1) / NE_,   e1_ = (ge0+1) % NE_;
    const int rv0 = recv_idx[e0_], sd0 = send_idx[e0_];
    const int rv1 = recv_idx[e1_], sd1 = send_idx[e1_];
    for (int i = tid; i < 2*8*T_; i += 256) {
        const int ed = i / 400, r = i % 400;
        const int c = r / T_, t = r % T_;
        const int node = (c < 4) ? (ed ? rv1 : rv0) : (ed ? sd1 : sd0);
        const int bsel = ed ? b1_ : b0_;
        const float v = states[((bsel*NO_ + node)*T_ + t)*SD_ + (c & 3)];
        x0Tb[ed*432 + (t + 1)*8 + c] = f2bf(v);
    }
    if (tid < 128) {
        const int edz = tid >> 6, c = tid & 63;
        const int bsel = edz ? b1_ : b0_, esel = edz ? e1_ : e0_;
        lat_bfb[edz*64 + c] = f2bf(latent[(bsel*NE_ + esel)*64 + c]);
    }
    __syncthreads();

    /* ---- stage 1: conv0 via MFMA (A shared) + rb conds (B shared) ---- */
    {
        const int t0a = ni * 32;
        const int sa = t0a + row0 + g0;
        const int sb = (ni == 0) ? (sa + 16) : (sa + 2);
        short8 a0 = AF[FI_C0A + (mi*2 + 0)*64 + lane];
        short8 a1 = AF[FI_C0A + (mi*2 + 1)*64 + lane];
        const f32x4 z4 = {0.f,0.f,0.f,0.f};
#pragma unroll
        for (int ed = 0; ed < 2; ++ed) {
            const unsigned short* xp = x0Tb + ed*432;
            short8 b0 = *(const short8*)&xp[sa * 8];
            short8 b1 = *(const short8*)&xp[sb * 8];
            f32x4 c00 = MFMA(a0, b0, z4), c01 = MFMA(a0, b1, z4);
            f32x4 c10 = MFMA(a1, b0, z4), c11 = MFMA(a1, b1, z4);
            unsigned short* xw = xTb + ed*XSTRIDE;
#pragma unroll
            for (int a = 0; a < 2; ++a) {
                const int fo0 = (mi*2 + a)*16 + g0*4;
                const f32x4 cb4 = *(const f32x4*)&cnnbf_b[fo0];
#pragma unroll
                for (int n = 0; n < 2; ++n) {
                    if (ni == 1 && n == 1 && row0 < 14) continue;
                    const int t = ((n == 0) ? t0a : (ni == 0 ? 16 : 34)) + row0;
                    const f32x4 A = (a == 0) ? ((n == 0) ? c00 : c01)
                                             : ((n == 0) ? c10 : c11);
                    const int rw = t + 2;
                    const int dix = rw*64 + ((((fo0 >> 3) ^ (rw & 7))) << 3) + (fo0 & 7);
                    u16x4 q;
                    q[0] = f2bf(swish_(A[0] + cb4[0]));
                    q[1] = f2bf(swish_(A[1] + cb4[1]));
                    q[2] = f2bf(swish_(A[2] + cb4[2]));
                    q[3] = f2bf(swish_(A[3] + cb4[3]));
                    *(u16x4*)&xw[dix] = q;
                }
            }
        }
        /* rb conds: wave = (rb, which); weight B-frags shared across edges */
        short8 la0_0 = *(const short8*)&lat_bfb[g0 * 8];
        short8 la1_0 = *(const short8*)&lat_bfb[32 + g0 * 8];
        short8 la0_1 = *(const short8*)&lat_bfb[64 + g0 * 8];
        short8 la1_1 = *(const short8*)&lat_bfb[96 + g0 * 8];
        const int rbq = wv >> 1, whq = wv & 1;
        const float* cbias = (whq ? rb_lfc2_b : rb_lfc1_b) + rbq*128;
#pragma unroll
        for (int q8 = 0; q8 < 8; ++q8) {
            short8 w0 = AF[FI_RBL + ((wv*8 + q8)*2 + 0)*64 + lane];
            short8 w1 = AF[FI_RBL + ((wv*8 + q8)*2 + 1)*64 + lane];
            f32x4 d0 = MFMA(la1_0, w1, MFMA(la0_0, w0, z4));
            f32x4 d1 = MFMA(la1_1, w1, MFMA(la0_1, w0, z4));
            if (g0 == 0) {
                const int o = q8*16 + row0;
                cond_sb[rbq*256 + whq*128 + o]       = d0[0] + cbias[o];
                cond_sb[512 + rbq*256 + whq*128 + o] = d1[0] + cbias[o];
            }
        }
    }
    __syncthreads();

    /* ---- stage 2: residual blocks (2 edges interleaved) ---- */
#pragma unroll 1
    for (int rb = 0; rb < 2; ++rb) {
        const float* c0 = cond_sb + rb*256;
        const float* c1 = cond_sb + 512 + rb*256;
        convpass2e<false>(AF, (rb*2 + 0)*2560, xTb, hTb, rb_conv1_b + rb*64,
                          c0, c0 + 64, c1, c1 + 64, lane, row0, g0, mi, ni);
        __syncthreads();
        convpass2e<true>(AF, (rb*2 + 1)*2560, hTb, xTb, rb_conv2_b + rb*64,
                         c0 + 128, c0 + 192, c1 + 128, c1 + 192, lane, row0, g0, mi, ni);
        __syncthreads();
    }

    /* ---- stage 3: windowed MLP fc1 (A shared) + folded mean ---- */
    {
        const int h = g0, nw = row0;
        f32x4 acc3[2];
        acc3[0] = (f32x4){0.f,0.f,0.f,0.f}; acc3[1] = acc3[0];
        const int nwe = (nw < 15) ? nw : 14;
        const int nwrow = 3*nwe + 2;
#pragma unroll
        for (int kk = 0; kk < 16; ++kk) {
            short8 a = AF[FI_FC1 + (wv*16 + kk)*64 + lane];
            const int row = nwrow + (kk >> 1);
            const int g   = ((kk & 1) << 2) + h;
            const int off = row*64 + ((g ^ (row & 7)) << 3);
#pragma unroll
            for (int ed = 0; ed < 2; ++ed) {
                short8 bfr = *(const short8*)&xTb[ed*XSTRIDE + off];
                acc3[ed] = MFMA(a, bfr, acc3[ed]);
            }
        }
        const f32x4 fb = *(const f32x4*)&mlp1_fc1_b[wv*16 + h*4];
#pragma unroll
        for (int ed = 0; ed < 2; ++ed) {
            float red[4];
#pragma unroll
            for (int r = 0; r < 4; ++r) {
                float v = (nw < 15) ? swish_(acc3[ed][r] + fb[r]) : 0.f;
                v += __shfl_xor(v, 1); v += __shfl_xor(v, 2);
                v += __shfl_xor(v, 4); v += __shfl_xor(v, 8);
                red[r] = v * (1.f / 15.f);
            }
            if (nw == 0) {
                f32x4 o4; o4[0] = red[0]; o4[1] = red[1]; o4[2] = red[2]; o4[3] = red[3];
                *(f32x4*)&hbar[(ge0 + ed)*64 + wv*16 + h*4] = o4;
            }
        }
    }
}

/* ---------------- tail: fc2 + 3 cond-MLP blocks + head, 64 edges/block ---- */
__global__ __launch_bounds__(256) void tail_kernel(
    const float* __restrict__ latent,
    const float* __restrict__ fc2b_g,
    const float* __restrict__ mlf1b, const float* __restrict__ mlf2b,
    const float* __restrict__ mll1b, const float* __restrict__ mll2b,
    const float* __restrict__ em_w, const float* __restrict__ em_b,
    const float* __restrict__ ws, const float* __restrict__ hbar,
    float* __restrict__ out) {

    const int m0 = blockIdx.x * 64;
    const int tid = threadIdx.x, lane = tid & 63, wv = tid >> 6;
    const int row15 = lane & 15, hgp = lane >> 4;
    const int o_l = wv*16 + row15;                 /* this lane's output col */

    __shared__ __align__(16) unsigned short Hb[2][64*64];  /* bf16, swizzled */
    __shared__ float V[64][68];                            /* fp32 running vec */
    __shared__ float em_s[64];

    const unsigned short* bfp = (const unsigned short*)((const char*)ws + 8192);
    const short8* AFp = (const short8*)bfp;

    if (tid < 64) em_s[tid] = em_w[tid];

    /* load hbar -> Hb[0] */
    {
        const int e = tid >> 2, q = tid & 3;
        const f32x4* src = (const f32x4*)&hbar[(m0 + e)*64 + q*16];
#pragma unroll
        for (int v4 = 0; v4 < 4; ++v4) {
            f32x4 x = src[v4];
            const int o0 = q*16 + v4*4;
            const int slot = o0 >> 3, half = (o0 >> 2) & 1;
            u16x4 p; p[0]=f2bf(x[0]); p[1]=f2bf(x[1]); p[2]=f2bf(x[2]); p[3]=f2bf(x[3]);
            *(u16x4*)&Hb[0][e*64 + ((slot ^ (e & 7)) << 3) + half*4] = p;
        }
    }
    __syncthreads();

    /* latent A-frags, cached */
    short8 lf[4][2];
#pragma unroll
    for (int m = 0; m < 4; ++m)
#pragma unroll
        for (int kk = 0; kk < 2; ++kk) {
            const float* lp = &latent[(m0 + m*16 + row15)*64 + kk*32 + hgp*8];
            f32x4 a = *(const f32x4*)lp, c = *(const f32x4*)(lp + 4);
            short8 f;
            f[0]=f2bf(a[0]); f[1]=f2bf(a[1]); f[2]=f2bf(a[2]); f[3]=f2bf(a[3]);
            f[4]=f2bf(c[0]); f[5]=f2bf(c[1]); f[6]=f2bf(c[2]); f[7]=f2bf(c[3]);
            lf[m][kk] = f;
        }

#define RD_A(buf, m, kk) \
    (*(const short8*)&Hb[buf][(m*16 + row15)*64 + ((((kk)*4 + hgp) ^ ((m*16 + row15) & 7)) << 3)])
#define RD_FCP(g, kk)  AFp[FI_FCP + (((g)*4 + wv)*2 + (kk))*64 + lane]
#define RD_CND(mb, nt, kk) AFp[FI_CONDP + (((mb)*16 + (nt))*2 + (kk))*64 + lane]

    /* GEMM0: stage3 fc2 */
    f32x4 D[4];
#pragma unroll
    for (int m = 0; m < 4; ++m) D[m] = (f32x4){0.f,0.f,0.f,0.f};
#pragma unroll
    for (int kk = 0; kk < 2; ++kk) {
        short8 bfr = RD_FCP(0, kk);
#pragma unroll
        for (int m = 0; m < 4; ++m) D[m] = MFMA(RD_A(0, m, kk), bfr, D[m]);
    }
    {
        const float bias = fc2b_g[o_l];
#pragma unroll
        for (int m = 0; m < 4; ++m)
#pragma unroll
            for (int r = 0; r < 4; ++r) {
                const int ee = m*16 + hgp*4 + r;
                const float v = D[m][r] + bias;
                V[ee][o_l] = v;
                Hb[1][ee*64 + ((((o_l >> 3) ^ (ee & 7))) << 3) + (o_l & 7)] = f2bf(v);
            }
    }
    __syncthreads();

    /* 3 cond-MLP blocks */
#pragma unroll 1
    for (int mb = 0; mb < 3; ++mb) {
        f32x4 G1[4], B1[4];
#pragma unroll
        for (int m = 0; m < 4; ++m) { G1[m] = (f32x4){0.f,0.f,0.f,0.f}; B1[m] = G1[m]; }
#pragma unroll
        for (int kk = 0; kk < 2; ++kk) {
            short8 bg = RD_CND(mb, wv,     kk);
            short8 bb = RD_CND(mb, wv + 4, kk);
#pragma unroll
            for (int m = 0; m < 4; ++m) {
                G1[m] = MFMA(lf[m][kk], bg, G1[m]);
                B1[m] = MFMA(lf[m][kk], bb, B1[m]);
            }
        }
        f32x4 D1[4];
#pragma unroll
        for (int m = 0; m < 4; ++m) D1[m] = (f32x4){0.f,0.f,0.f,0.f};
#pragma unroll
        for (int kk = 0; kk < 2; ++kk) {
            short8 bfr = RD_FCP(1 + mb*2, kk);
#pragma unroll
            for (int m = 0; m < 4; ++m) D1[m] = MFMA(RD_A(1, m, kk), bfr, D1[m]);
        }
        {
            const float bfc  = mlf1b[mb*64 + o_l];
            const float bg1  = mll1b[mb*128 + o_l];
            const float bb1  = mll1b[mb*128 + 64 + o_l];
#pragma unroll
            for (int m = 0; m < 4; ++m)
#pragma unroll
                for (int r = 0; r < 4; ++r) {
                    const int ee = m*16 + hgp*4 + r;
                    const float h1 = swish_((G1[m][r] + bg1) * (D1[m][r] + bfc)
                                            + (B1[m][r] + bb1));
                    Hb[0][ee*64 + ((((o_l >> 3) ^ (ee & 7))) << 3) + (o_l & 7)] = f2bf(h1);
                }
        }
        __syncthreads();

        f32x4 G2[4], B2[4];
#pragma unroll
        for (int m = 0; m < 4; ++m) { G2[m] = (f32x4){0.f,0.f,0.f,0.f}; B2[m] = G2[m]; }
#pragma unroll
        for (int kk = 0; kk < 2; ++kk) {
            short8 bg = RD_CND(mb, wv + 8,  kk);
            short8 bb = RD_CND(mb, wv + 12, kk);
#pragma unroll
            for (int m = 0; m < 4; ++m) {
                G2[m] = MFMA(lf[m][kk], bg, G2[m]);
                B2[m] = MFMA(lf[m][kk], bb, B2[m]);
            }
        }
        f32x4 D2[4];
#pragma unroll
        for (int m = 0; m < 4; ++m) D2[m] = (f32x4){0.f,0.f,0.f,0.f};
#pragma unroll
        for (int kk = 0; kk < 2; ++kk) {
            short8 bfr = RD_FCP(2 + mb*2, kk);
#pragma unroll
            for (int m = 0; m < 4; ++m) D2[m] = MFMA(RD_A(0, m, kk), bfr, D2[m]);
        }
        {
            const float bfc  = mlf2b[mb*64 + o_l];
            const float bg2  = mll2b[mb*128 + o_l];
            const float bb2  = mll2b[mb*128 + 64 + o_l];
#pragma unroll
            for (int m = 0; m < 4; ++m)
#pragma unroll
                for (int r = 0; r < 4; ++r) {
                    const int ee = m*16 + hgp*4 + r;
                    const float add = swish_((G2[m][r] + bg2) * (D2[m][r] + bfc)
                                             + (B2[m][r] + bb2));
                    const float vn = V[ee][o_l] + add;
                    V[ee][o_l] = vn;
                    Hb[1][ee*64 + ((((o_l >> 3) ^ (ee & 7))) << 3) + (o_l & 7)] = f2bf(vn);
                }
        }
        __syncthreads();
    }

    /* head */
    if (tid < 64) {
        const int ee = tid;
        float acc = em_b[0];
#pragma unroll 16
        for (int j = 0; j < 64; ++j) {
            const int o = (j + ee) & 63;
            acc += V[ee][o] * em_s[o];
        }
        out[m0 + ee] = acc;
    }
}

extern "C" void kernel_launch(void* const* d_in, const int* in_sizes, int n_in,
                              void* d_out, int out_size, void* d_ws, size_t ws_size,
                              hipStream_t stream) {
    const float* states   = (const float*)d_in[0];
    const float* latent   = (const float*)d_in[1];
    const float* cnnbf_w  = (const float*)d_in[2];
    const float* cnnbf_b  = (const float*)d_in[3];
    const float* rb1w     = (const float*)d_in[4];
    const float* rb1b     = (const float*)d_in[5];
    const float* rb2w     = (const float*)d_in[6];
    const float* rb2b     = (const float*)d_in[7];
    const float* rbl1w    = (const float*)d_in[8];
    const float* rbl1b    = (const float*)d_in[9];
    const float* rbl2w    = (const float*)d_in[10];
    const float* rbl2b    = (const float*)d_in[11];
    const float* fc1w     = (const float*)d_in[12];
    const float* fc1b     = (const float*)d_in[13];
    const float* fc2w     = (const float*)d_in[14];
    const float* fc2b     = (const float*)d_in[15];
    const float* mlf1w    = (const float*)d_in[16];
    const float* mlf1b    = (const float*)d_in[17];
    const float* mlf2w    = (const float*)d_in[18];
    const float* mlf2b    = (const float*)d_in[19];
    const float* mll1w    = (const float*)d_in[20];
    const float* mll1b    = (const float*)d_in[21];
    const float* mll2w    = (const float*)d_in[22];
    const float* mll2b    = (const float*)d_in[23];
    const float* em_w     = (const float*)d_in[24];
    const float* em_b     = (const float*)d_in[25];
    const int*   recv_idx = (const int*)d_in[26];
    const int*   send_idx = (const int*)d_in[27];
    float* ws  = (float*)d_ws;
    float* out = (float*)d_out;
    float* hbar = ws + HBAR_F32;

    prep_kernel<<<(N_BF16 + 255) / 256, 256, 0, stream>>>(
        cnnbf_w, rb1w, rb2w, fc1w, fc2w, rbl1w, rbl2w, mll1w, mll2w, mlf1w, mlf2w, ws);

    mega_kernel<<<B_ * NE_ / 2, 256, 0, stream>>>(
        states, latent, cnnbf_b, rb1b, rb2b, rbl1b, rbl2b, fc1b,
        recv_idx, send_idx, ws, hbar);

    tail_kernel<<<(B_ * NE_) / 64, 256, 0, stream>>>(
        latent, fc2b, mlf1b, mlf2b, mll1b, mll2b, em_w, em_b, ws, hbar, out);
}

// Round 6
// 352.320 us; speedup vs baseline: 9.6933x; 1.0430x over previous
//
#include <hip/hip_runtime.h>

#define B_      2
#define NO_     96
#define T_      50
#define SD_     4
#define NE_     (NO_*(NO_-1))   /* 9120 */
#define F_      64
#define NW_     15

typedef __attribute__((ext_vector_type(8))) short  short8;   /* bf16x8 MFMA frag */
typedef __attribute__((ext_vector_type(4))) float  f32x4;
typedef __attribute__((ext_vector_type(4))) unsigned short u16x4;
typedef __attribute__((ext_vector_type(2))) unsigned int   u32x2;

/* ---- ws layout: bf16 pool (ushort) at byte 8192, element offsets ---- */
#define E_CONVA 0        /* [4 conv][4 m][10 kk][64][8]      = 81920 */
#define E_FC1A  81920    /* [4 m][16 kk][64][8] k=kt*64+f    = 32768 */
#define E_RBL   114688   /* rb cond frags [32 nt][2 kk][64][8]=32768 */
#define E_CONDP 147456   /* [3 mb][16 nt][2 kk][64][8]       = 49152 */
#define E_FCP   196608   /* [7 g][4 nt][2 kk][64][8]         = 28672 */
#define E_C0A   225280   /* conv0 A frags [4 m][64][8]       = 2048  */
#define N_BF16  227328
#define HBAR_F32 115712          /* float offset: (8192 + 2*N_BF16)/4 */

/* frag-index bases (element offset / 8) */
#define FI_FC1   10240
#define FI_RBL   14336
#define FI_CONDP 18432
#define FI_FCP   24576
#define FI_C0A   28160

#define XSTRIDE  3456            /* 54*64 ushorts per edge buffer */

#define MFMA(a, b, c) __builtin_amdgcn_mfma_f32_16x16x32_bf16(a, b, c, 0, 0, 0)

/* fast swish: v * rcp(1+exp(-v)); v_rcp_f32 ~1ulp, fine vs 1.7e-2 threshold */
__device__ __forceinline__ float swish_(float v) {
    return v * __builtin_amdgcn_rcpf(1.f + __expf(-v));
}

__device__ __forceinline__ unsigned short f2bf(float f) {
    unsigned u = __float_as_uint(f);
    u += 0x7FFFu + ((u >> 16) & 1u);
    return (unsigned short)(u >> 16);
}
__device__ __forceinline__ float bf2f(unsigned short u) {
    return __uint_as_float(((unsigned)u) << 16);
}
/* 2×f32 -> packed bf16 pair in one instr (RNE) */
__device__ __forceinline__ unsigned cvtpk(float lo, float hi) {
    unsigned r;
    asm("v_cvt_pk_bf16_f32 %0, %1, %2" : "=v"(r) : "v"(lo), "v"(hi));
    return r;
}

/* ------------------------------------------------------------------ */
__global__ void prep_kernel(const float* __restrict__ cnnbf_w,
                            const float* __restrict__ rb1w, const float* __restrict__ rb2w,
                            const float* __restrict__ fc1w, const float* __restrict__ fc2w,
                            const float* __restrict__ rbl1w, const float* __restrict__ rbl2w,
                            const float* __restrict__ mll1w, const float* __restrict__ mll2w,
                            const float* __restrict__ mlf1w, const float* __restrict__ mlf2w,
                            float* __restrict__ ws) {
    int e = blockIdx.x * blockDim.x + threadIdx.x;
    if (e >= N_BF16) return;
    unsigned short* bfp = (unsigned short*)((char*)ws + 8192);
    float v;
    if (e < E_FC1A) {                               /* conv A frags (k = tap*64+fi) */
        int r = e & 511, fid = e >> 9;
        int lane = r >> 3, j = r & 7;
        int kk = fid % 10, m = (fid / 10) & 3, c = fid / 40;
        int fo = m*16 + (lane & 15);
        int kidx = kk*32 + (lane >> 4)*8 + j;
        int k = kidx >> 6, fi = kidx & 63;
        int i = c >> 1;
        const float* src = (c & 1) ? rb2w : rb1w;
        v = src[((i*64 + fo)*64 + fi)*5 + k];
    } else if (e < E_RBL) {                         /* fc1 A frags, k = kt*64+f */
        int e2 = e - E_FC1A;
        int r = e2 & 511, fid = e2 >> 9;
        int lane = r >> 3, j = r & 7;
        int kk = fid & 15, m = fid >> 4;
        int fo = m*16 + (lane & 15);
        int k = kk*32 + (lane >> 4)*8 + j;
        int krow = (k & 63)*8 + (k >> 6);           /* original index = f*8 + kt */
        v = fc1w[fo*512 + krow];
    } else if (e < E_CONDP) {                       /* rb cond B frags */
        int e3 = e - E_RBL;
        int j = e3 & 7, lane = (e3 >> 3) & 63, fid = e3 >> 9;
        int kk = fid & 1, nt = fid >> 1;            /* nt in [0,32) */
        int rb = nt >> 4, which = (nt >> 3) & 1, ot = nt & 7;
        int o = ot*16 + (lane & 15);
        int k = kk*32 + (lane >> 4)*8 + j;
        const float* src = which ? rbl2w : rbl1w;
        v = src[(rb*128 + o)*64 + k];
    } else if (e < E_FCP) {                         /* mb cond B frags */
        int e4 = e - E_CONDP;
        int r = e4 & 511, fid = e4 >> 9;            /* fid = (mb*16+nt)*2+kk */
        int lane = r >> 3, j = r & 7;
        int kk = fid & 1, nt = (fid >> 1) & 15, mb = fid >> 5;
        int n = nt*16 + (lane & 15);
        int which = n >> 7, o = n & 127;
        int k = kk*32 + (lane >> 4)*8 + j;
        const float* src = which ? mll2w : mll1w;
        v = src[(mb*128 + o)*64 + k];
    } else if (e < E_C0A) {                         /* tail fc B frags */
        int e5 = e - E_FCP;
        int r = e5 & 511, fid = e5 >> 9;            /* fid = (g*4+nt)*2+kk */
        int lane = r >> 3, j = r & 7;
        int kk = fid & 1, nt = (fid >> 1) & 3, g = fid >> 3;
        int o = nt*16 + (lane & 15);
        int k = kk*32 + (lane >> 4)*8 + j;
        if (g == 0) v = fc2w[o*64 + k];
        else {
            int mb = (g - 1) >> 1;
            const float* src = ((g - 1) & 1) ? mlf2w : mlf1w;
            v = src[(mb*64 + o)*64 + k];
        }
    } else {                                        /* conv0 A frags (K=24 pad 32) */
        int e6 = e - E_C0A;
        int j = e6 & 7, lane = (e6 >> 3) & 63, m = e6 >> 9;
        int fo = m*16 + (lane & 15);
        int k = (lane >> 4)*8 + j;
        int tap = k >> 3, fi = k & 7;
        v = (tap < 3) ? cnnbf_w[(fo*8 + fi)*3 + tap] : 0.f;
    }
    bfp[e] = f2bf(v);
}

/* ---------------- conv 64->64 k=5 via MFMA, wave=(mi,ni), 2 edges --
   A-fragments loaded ONCE per wave and reused for both edges.
   ISCONV2: residual accumulates in fp32 REGISTERS (xreg), no LDS RMW. */
template<bool ISCONV2>
__device__ __forceinline__ void convpass2e(const short8* __restrict__ AF, int fb,
        const unsigned short* __restrict__ Bb, unsigned short* __restrict__ Db,
        const float* __restrict__ cb,
        const float* __restrict__ gv0, const float* __restrict__ bv0,
        const float* __restrict__ gv1, const float* __restrict__ bv1,
        f32x4 (&xreg)[2][2][2], const int (&dixs)[2][2], bool skip1,
        int lane, int row0, int g0, int mi, int ni) {
    const int t0a = ni * 32;
    f32x4 acc[2][4];
#pragma unroll
    for (int ed = 0; ed < 2; ++ed)
#pragma unroll
        for (int q = 0; q < 4; ++q) acc[ed][q] = (f32x4){0.f,0.f,0.f,0.f};
#pragma unroll
    for (int kk = 0; kk < 10; ++kk) {
        short8 a0 = AF[fb + ((mi*2 + 0)*10 + kk)*64 + lane];
        short8 a1 = AF[fb + ((mi*2 + 1)*10 + kk)*64 + lane];
        const int c  = ((kk & 1) << 2) + g0;
        const int sa = t0a + row0 + (kk >> 1);
        const int ia = sa*64 + ((c ^ (sa & 7)) << 3);
        int ib;
        if (ni == 0) ib = ia + 1024;
        else { const int sb2 = sa + 2; ib = sb2*64 + ((c ^ (sb2 & 7)) << 3); }
#pragma unroll
        for (int ed = 0; ed < 2; ++ed) {
            const unsigned short* Bs = Bb + ed*XSTRIDE;
            short8 b0 = *(const short8*)&Bs[ia];
            short8 b1 = *(const short8*)&Bs[ib];
            acc[ed][0] = MFMA(a0, b0, acc[ed][0]);
            acc[ed][1] = MFMA(a0, b1, acc[ed][1]);
            acc[ed][2] = MFMA(a1, b0, acc[ed][2]);
            acc[ed][3] = MFMA(a1, b1, acc[ed][3]);
        }
    }
#pragma unroll
    for (int ed = 0; ed < 2; ++ed) {
        const float* gv = ed ? gv1 : gv0;
        const float* bv = ed ? bv1 : bv0;
        unsigned short* Dst = Db + ed*XSTRIDE;
#pragma unroll
        for (int a = 0; a < 2; ++a) {
            const int fo0 = (mi*2 + a)*16 + g0*4;
            const f32x4 cb4 = *(const f32x4*)&cb[fo0];
            const f32x4 g4  = *(const f32x4*)&gv[fo0];
            const f32x4 b4  = *(const f32x4*)&bv[fo0];
            f32x4 gcb;
            gcb[0] = g4[0]*cb4[0] + b4[0]; gcb[1] = g4[1]*cb4[1] + b4[1];
            gcb[2] = g4[2]*cb4[2] + b4[2]; gcb[3] = g4[3]*cb4[3] + b4[3];
#pragma unroll
            for (int n = 0; n < 2; ++n) {
                if (n == 1 && skip1) continue;
                const f32x4 A = acc[ed][a*2 + n];
                float s0 = swish_(g4[0]*A[0] + gcb[0]);
                float s1 = swish_(g4[1]*A[1] + gcb[1]);
                float s2 = swish_(g4[2]*A[2] + gcb[2]);
                float s3 = swish_(g4[3]*A[3] + gcb[3]);
                if (ISCONV2) {
                    f32x4& xr = xreg[ed][a][n];
                    s0 = (xr[0] += s0); s1 = (xr[1] += s1);
                    s2 = (xr[2] += s2); s3 = (xr[3] += s3);
                }
                *(u32x2*)&Dst[dixs[a][n]] = (u32x2){cvtpk(s0, s1), cvtpk(s2, s3)};
            }
        }
    }
}

/* ------------------------------------------------------------------ */
__global__ __launch_bounds__(256, 4) void mega_kernel(
    const float* __restrict__ states, const float* __restrict__ latent,
    const float* __restrict__ cnnbf_b,
    const float* __restrict__ rb_conv1_b, const float* __restrict__ rb_conv2_b,
    const float* __restrict__ rb_lfc1_b, const float* __restrict__ rb_lfc2_b,
    const float* __restrict__ mlp1_fc1_b,
    const int* __restrict__ recv_idx, const int* __restrict__ send_idx,
    const float* __restrict__ ws, float* __restrict__ hbar) {

    const int ge0 = blockIdx.x * 2;                /* two edges per block */
    const int tid  = threadIdx.x;
    const int lane = tid & 63;
    const int wv   = tid >> 6;
    const int row0 = lane & 15, g0 = lane >> 4;
    const int mi = wv & 1, ni = wv >> 1;

    __shared__ __align__(16) unsigned short xTb[2*54*64];  /* bf16 trunk, swizzled */
    __shared__ __align__(16) unsigned short hTb[2*54*64];
    __shared__ __align__(16) unsigned short x0Tb[2*54*8];  /* bf16 input, [row][fi] */
    __shared__ __align__(16) unsigned short lat_bfb[2*64];
    __shared__ __align__(16) float cond_sb[2*512];

    const unsigned short* bfp = (const unsigned short*)((const char*)ws + 8192);
    const short8* AF = (const short8*)bfp;

    /* per-wave output-tile addresses (invariant across all conv passes) */
    int dixs[2][2];
    const bool skip1 = (ni == 1) && (row0 < 14);
#pragma unroll
    for (int a = 0; a < 2; ++a) {
        const int fo0 = (mi*2 + a)*16 + g0*4;
#pragma unroll
        for (int n = 0; n < 2; ++n) {
            const int t = ((n == 0) ? ni*32 : (ni == 0 ? 16 : 34)) + row0;
            const int rw = t + 2;
            dixs[a][n] = rw*64 + ((((fo0 >> 3) ^ (rw & 7))) << 3) + (fo0 & 7);
        }
    }
    f32x4 xreg[2][2][2];                           /* fp32 trunk residual in regs */

    /* ---- stage 0: zero pads, gather both edges ---- */
    for (int z = tid; z < 512; z += 256) {
        const int edz = z >> 8, rr = (z >> 6) & 3, cc = z & 63;
        const int row = (rr < 2) ? rr : 50 + rr;
        xTb[edz*XSTRIDE + row*64 + cc] = 0;
        hTb[edz*XSTRIDE + row*64 + cc] = 0;
    }
    if (tid < 8) {
        const int edz = tid >> 2, q = tid & 3;
        const int rz = (q == 0) ? 0 : 50 + q;
        short8 zz = {0,0,0,0,0,0,0,0};
        *(short8*)&x0Tb[edz*432 + rz*8] = zz;
    }
    const int b0_ = ge0 / NE_,       e0_ = ge0 % NE_;
    const int b1_ = (ge0+1) / NE_,   e1_ = (ge0+1) % NE_;
    const int rv0 = recv_idx[e0_], sd0 = send_idx[e0_];
    const int rv1 = recv_idx[e1_], sd1 = send_idx[e1_];
    for (int i = tid; i < 2*8*T_; i += 256) {
        const int ed = i / 400, r = i % 400;
        const int c = r / T_, t = r % T_;
        const int node = (c < 4) ? (ed ? rv1 : rv0) : (ed ? sd1 : sd0);
        const int bsel = ed ? b1_ : b0_;
        const float v = states[((bsel*NO_ + node)*T_ + t)*SD_ + (c & 3)];
        x0Tb[ed*432 + (t + 1)*8 + c] = f2bf(v);
    }
    if (tid < 128) {
        const int edz = tid >> 6, c = tid & 63;
        const int bsel = edz ? b1_ : b0_, esel = edz ? e1_ : e0_;
        lat_bfb[edz*64 + c] = f2bf(latent[(bsel*NE_ + esel)*64 + c]);
    }
    __syncthreads();

    /* ---- stage 1: conv0 via MFMA (A shared) + rb conds (B shared) ---- */
    {
        const int t0a = ni * 32;
        const int sa = t0a + row0 + g0;
        const int sb = (ni == 0) ? (sa + 16) : (sa + 2);
        short8 a0 = AF[FI_C0A + (mi*2 + 0)*64 + lane];
        short8 a1 = AF[FI_C0A + (mi*2 + 1)*64 + lane];
        const f32x4 z4 = {0.f,0.f,0.f,0.f};
#pragma unroll
        for (int ed = 0; ed < 2; ++ed) {
            const unsigned short* xp = x0Tb + ed*432;
            short8 b0 = *(const short8*)&xp[sa * 8];
            short8 b1 = *(const short8*)&xp[sb * 8];
            f32x4 c00 = MFMA(a0, b0, z4), c01 = MFMA(a0, b1, z4);
            f32x4 c10 = MFMA(a1, b0, z4), c11 = MFMA(a1, b1, z4);
            unsigned short* xw = xTb + ed*XSTRIDE;
#pragma unroll
            for (int a = 0; a < 2; ++a) {
                const int fo0 = (mi*2 + a)*16 + g0*4;
                const f32x4 cb4 = *(const f32x4*)&cnnbf_b[fo0];
#pragma unroll
                for (int n = 0; n < 2; ++n) {
                    if (n == 1 && skip1) continue;
                    const f32x4 A = (a == 0) ? ((n == 0) ? c00 : c01)
                                             : ((n == 0) ? c10 : c11);
                    f32x4& xr = xreg[ed][a][n];
                    xr[0] = swish_(A[0] + cb4[0]);
                    xr[1] = swish_(A[1] + cb4[1]);
                    xr[2] = swish_(A[2] + cb4[2]);
                    xr[3] = swish_(A[3] + cb4[3]);
                    *(u32x2*)&xw[dixs[a][n]] = (u32x2){cvtpk(xr[0], xr[1]),
                                                       cvtpk(xr[2], xr[3])};
                }
            }
        }
        /* rb conds: wave = (rb, which); weight B-frags shared across edges */
        short8 la0_0 = *(const short8*)&lat_bfb[g0 * 8];
        short8 la1_0 = *(const short8*)&lat_bfb[32 + g0 * 8];
        short8 la0_1 = *(const short8*)&lat_bfb[64 + g0 * 8];
        short8 la1_1 = *(const short8*)&lat_bfb[96 + g0 * 8];
        const int rbq = wv >> 1, whq = wv & 1;
        const float* cbias = (whq ? rb_lfc2_b : rb_lfc1_b) + rbq*128;
#pragma unroll
        for (int q8 = 0; q8 < 8; ++q8) {
            short8 w0 = AF[FI_RBL + ((wv*8 + q8)*2 + 0)*64 + lane];
            short8 w1 = AF[FI_RBL + ((wv*8 + q8)*2 + 1)*64 + lane];
            f32x4 d0 = MFMA(la1_0, w1, MFMA(la0_0, w0, z4));
            f32x4 d1 = MFMA(la1_1, w1, MFMA(la0_1, w0, z4));
            if (g0 == 0) {
                const int o = q8*16 + row0;
                cond_sb[rbq*256 + whq*128 + o]       = d0[0] + cbias[o];
                cond_sb[512 + rbq*256 + whq*128 + o] = d1[0] + cbias[o];
            }
        }
    }
    __syncthreads();

    /* ---- stage 2: residual blocks (2 edges interleaved) ---- */
#pragma unroll 1
    for (int rb = 0; rb < 2; ++rb) {
        const float* c0 = cond_sb + rb*256;
        const float* c1 = cond_sb + 512 + rb*256;
        convpass2e<false>(AF, (rb*2 + 0)*2560, xTb, hTb, rb_conv1_b + rb*64,
                          c0, c0 + 64, c1, c1 + 64, xreg, dixs, skip1,
                          lane, row0, g0, mi, ni);
        __syncthreads();
        convpass2e<true>(AF, (rb*2 + 1)*2560, hTb, xTb, rb_conv2_b + rb*64,
                         c0 + 128, c0 + 192, c1 + 128, c1 + 192, xreg, dixs, skip1,
                         lane, row0, g0, mi, ni);
        __syncthreads();
    }

    /* ---- stage 3: windowed MLP fc1 (A shared) + folded mean ---- */
    {
        const int h = g0, nw = row0;
        f32x4 acc3[2];
        acc3[0] = (f32x4){0.f,0.f,0.f,0.f}; acc3[1] = acc3[0];
        const int nwe = (nw < 15) ? nw : 14;
        const int nwrow = 3*nwe + 2;
#pragma unroll
        for (int kk = 0; kk < 16; ++kk) {
            short8 a = AF[FI_FC1 + (wv*16 + kk)*64 + lane];
            const int row = nwrow + (kk >> 1);
            const int g   = ((kk & 1) << 2) + h;
            const int off = row*64 + ((g ^ (row & 7)) << 3);
#pragma unroll
            for (int ed = 0; ed < 2; ++ed) {
                short8 bfr = *(const short8*)&xTb[ed*XSTRIDE + off];
                acc3[ed] = MFMA(a, bfr, acc3[ed]);
            }
        }
        const f32x4 fb = *(const f32x4*)&mlp1_fc1_b[wv*16 + h*4];
#pragma unroll
        for (int ed = 0; ed < 2; ++ed) {
            float red[4];
#pragma unroll
            for (int r = 0; r < 4; ++r) {
                float v = (nw < 15) ? swish_(acc3[ed][r] + fb[r]) : 0.f;
                v += __shfl_xor(v, 1); v += __shfl_xor(v, 2);
                v += __shfl_xor(v, 4); v += __shfl_xor(v, 8);
                red[r] = v * (1.f / 15.f);
            }
            if (nw == 0) {
                f32x4 o4; o4[0] = red[0]; o4[1] = red[1]; o4[2] = red[2]; o4[3] = red[3];
                *(f32x4*)&hbar[(ge0 + ed)*64 + wv*16 + h*4] = o4;
            }
        }
    }
}

/* ---------------- tail: fc2 + 3 cond-MLP blocks + head, 64 edges/block ---- */
__global__ __launch_bounds__(256) void tail_kernel(
    const float* __restrict__ latent,
    const float* __restrict__ fc2b_g,
    const float* __restrict__ mlf1b, const float* __restrict__ mlf2b,
    const float* __restrict__ mll1b, const float* __restrict__ mll2b,
    const float* __restrict__ em_w, const float* __restrict__ em_b,
    const float* __restrict__ ws, const float* __restrict__ hbar,
    float* __restrict__ out) {

    const int m0 = blockIdx.x * 64;
    const int tid = threadIdx.x, lane = tid & 63, wv = tid >> 6;
    const int row15 = lane & 15, hgp = lane >> 4;
    const int o_l = wv*16 + row15;                 /* this lane's output col */

    __shared__ __align__(16) unsigned short Hb[2][64*64];  /* bf16, swizzled */
    __shared__ float V[64][68];                            /* fp32 running vec */
    __shared__ float em_s[64];

    const unsigned short* bfp = (const unsigned short*)((const char*)ws + 8192);
    const short8* AFp = (const short8*)bfp;

    if (tid < 64) em_s[tid] = em_w[tid];

    /* load hbar -> Hb[0] */
    {
        const int e = tid >> 2, q = tid & 3;
        const f32x4* src = (const f32x4*)&hbar[(m0 + e)*64 + q*16];
#pragma unroll
        for (int v4 = 0; v4 < 4; ++v4) {
            f32x4 x = src[v4];
            const int o0 = q*16 + v4*4;
            const int slot = o0 >> 3, half = (o0 >> 2) & 1;
            u16x4 p; p[0]=f2bf(x[0]); p[1]=f2bf(x[1]); p[2]=f2bf(x[2]); p[3]=f2bf(x[3]);
            *(u16x4*)&Hb[0][e*64 + ((slot ^ (e & 7)) << 3) + half*4] = p;
        }
    }
    __syncthreads();

    /* latent A-frags, cached */
    short8 lf[4][2];
#pragma unroll
    for (int m = 0; m < 4; ++m)
#pragma unroll
        for (int kk = 0; kk < 2; ++kk) {
            const float* lp = &latent[(m0 + m*16 + row15)*64 + kk*32 + hgp*8];
            f32x4 a = *(const f32x4*)lp, c = *(const f32x4*)(lp + 4);
            short8 f;
            f[0]=f2bf(a[0]); f[1]=f2bf(a[1]); f[2]=f2bf(a[2]); f[3]=f2bf(a[3]);
            f[4]=f2bf(c[0]); f[5]=f2bf(c[1]); f[6]=f2bf(c[2]); f[7]=f2bf(c[3]);
            lf[m][kk] = f;
        }

#define RD_A(buf, m, kk) \
    (*(const short8*)&Hb[buf][(m*16 + row15)*64 + ((((kk)*4 + hgp) ^ ((m*16 + row15) & 7)) << 3)])
#define RD_FCP(g, kk)  AFp[FI_FCP + (((g)*4 + wv)*2 + (kk))*64 + lane]
#define RD_CND(mb, nt, kk) AFp[FI_CONDP + (((mb)*16 + (nt))*2 + (kk))*64 + lane]

    /* GEMM0: stage3 fc2 */
    f32x4 D[4];
#pragma unroll
    for (int m = 0; m < 4; ++m) D[m] = (f32x4){0.f,0.f,0.f,0.f};
#pragma unroll
    for (int kk = 0; kk < 2; ++kk) {
        short8 bfr = RD_FCP(0, kk);
#pragma unroll
        for (int m = 0; m < 4; ++m) D[m] = MFMA(RD_A(0, m, kk), bfr, D[m]);
    }
    {
        const float bias = fc2b_g[o_l];
#pragma unroll
        for (int m = 0; m < 4; ++m)
#pragma unroll
            for (int r = 0; r < 4; ++r) {
                const int ee = m*16 + hgp*4 + r;
                const float v = D[m][r] + bias;
                V[ee][o_l] = v;
                Hb[1][ee*64 + ((((o_l >> 3) ^ (ee & 7))) << 3) + (o_l & 7)] = f2bf(v);
            }
    }
    __syncthreads();

    /* 3 cond-MLP blocks */
#pragma unroll 1
    for (int mb = 0; mb < 3; ++mb) {
        f32x4 G1[4], B1[4];
#pragma unroll
        for (int m = 0; m < 4; ++m) { G1[m] = (f32x4){0.f,0.f,0.f,0.f}; B1[m] = G1[m]; }
#pragma unroll
        for (int kk = 0; kk < 2; ++kk) {
            short8 bg = RD_CND(mb, wv,     kk);
            short8 bb = RD_CND(mb, wv + 4, kk);
#pragma unroll
            for (int m = 0; m < 4; ++m) {
                G1[m] = MFMA(lf[m][kk], bg, G1[m]);
                B1[m] = MFMA(lf[m][kk], bb, B1[m]);
            }
        }
        f32x4 D1[4];
#pragma unroll
        for (int m = 0; m < 4; ++m) D1[m] = (f32x4){0.f,0.f,0.f,0.f};
#pragma unroll
        for (int kk = 0; kk < 2; ++kk) {
            short8 bfr = RD_FCP(1 + mb*2, kk);
#pragma unroll
            for (int m = 0; m < 4; ++m) D1[m] = MFMA(RD_A(1, m, kk), bfr, D1[m]);
        }
        {
            const float bfc  = mlf1b[mb*64 + o_l];
            const float bg1  = mll1b[mb*128 + o_l];
            const float bb1  = mll1b[mb*128 + 64 + o_l];
#pragma unroll
            for (int m = 0; m < 4; ++m)
#pragma unroll
                for (int r = 0; r < 4; ++r) {
                    const int ee = m*16 + hgp*4 + r;
                    const float h1 = swish_((G1[m][r] + bg1) * (D1[m][r] + bfc)
                                            + (B1[m][r] + bb1));
                    Hb[0][ee*64 + ((((o_l >> 3) ^ (ee & 7))) << 3) + (o_l & 7)] = f2bf(h1);
                }
        }
        __syncthreads();

        f32x4 G2[4], B2[4];
#pragma unroll
        for (int m = 0; m < 4; ++m) { G2[m] = (f32x4){0.f,0.f,0.f,0.f}; B2[m] = G2[m]; }
#pragma unroll
        for (int kk = 0; kk < 2; ++kk) {
            short8 bg = RD_CND(mb, wv + 8,  kk);
            short8 bb = RD_CND(mb, wv + 12, kk);
#pragma unroll
            for (int m = 0; m < 4; ++m) {
                G2[m] = MFMA(lf[m][kk], bg, G2[m]);
                B2[m] = MFMA(lf[m][kk], bb, B2[m]);
            }
        }
        f32x4 D2[4];
#pragma unroll
        for (int m = 0; m < 4; ++m) D2[m] = (f32x4){0.f,0.f,0.f,0.f};
#pragma unroll
        for (int kk = 0; kk < 2; ++kk) {
            short8 bfr = RD_FCP(2 + mb*2, kk);
#pragma unroll
            for (int m = 0; m < 4; ++m) D2[m] = MFMA(RD_A(0, m, kk), bfr, D2[m]);
        }
        {
            const float bfc  = mlf2b[mb*64 + o_l];
            const float bg2  = mll2b[mb*128 + o_l];
            const float bb2  = mll2b[mb*128 + 64 + o_l];
#pragma unroll
            for (int m = 0; m < 4; ++m)
#pragma unroll
                for (int r = 0; r < 4; ++r) {
                    const int ee = m*16 + hgp*4 + r;
                    const float add = swish_((G2[m][r] + bg2) * (D2[m][r] + bfc)
                                             + (B2[m][r] + bb2));
                    const float vn = V[ee][o_l] + add;
                    V[ee][o_l] = vn;
                    Hb[1][ee*64 + ((((o_l >> 3) ^ (ee & 7))) << 3) + (o_l & 7)] = f2bf(vn);
                }
        }
        __syncthreads();
    }

    /* head */
    if (tid < 64) {
        const int ee = tid;
        float acc = em_b[0];
#pragma unroll 16
        for (int j = 0; j < 64; ++j) {
            const int o = (j + ee) & 63;
            acc += V[ee][o] * em_s[o];
        }
        out[m0 + ee] = acc;
    }
}

extern "C" void kernel_launch(void* const* d_in, const int* in_sizes, int n_in,
                              void* d_out, int out_size, void* d_ws, size_t ws_size,
                              hipStream_t stream) {
    const float* states   = (const float*)d_in[0];
    const float* latent   = (const float*)d_in[1];
    const float* cnnbf_w  = (const float*)d_in[2];
    const float* cnnbf_b  = (const float*)d_in[3];
    const float* rb1w     = (const float*)d_in[4];
    const float* rb1b     = (const float*)d_in[5];
    const float* rb2w     = (const float*)d_in[6];
    const float* rb2b     = (const float*)d_in[7];
    const float* rbl1w    = (const float*)d_in[8];
    const float* rbl1b    = (const float*)d_in[9];
    const float* rbl2w    = (const float*)d_in[10];
    const float* rbl2b    = (const float*)d_in[11];
    const float* fc1w     = (const float*)d_in[12];
    const float* fc1b     = (const float*)d_in[13];
    const float* fc2w     = (const float*)d_in[14];
    const float* fc2b     = (const float*)d_in[15];
    const float* mlf1w    = (const float*)d_in[16];
    const float* mlf1b    = (const float*)d_in[17];
    const float* mlf2w    = (const float*)d_in[18];
    const float* mlf2b    = (const float*)d_in[19];
    const float* mll1w    = (const float*)d_in[20];
    const float* mll1b    = (const float*)d_in[21];
    const float* mll2w    = (const float*)d_in[22];
    const float* mll2b    = (const float*)d_in[23];
    const float* em_w     = (const float*)d_in[24];
    const float* em_b     = (const float*)d_in[25];
    const int*   recv_idx = (const int*)d_in[26];
    const int*   send_idx = (const int*)d_in[27];
    float* ws  = (float*)d_ws;
    float* out = (float*)d_out;
    float* hbar = ws + HBAR_F32;

    prep_kernel<<<(N_BF16 + 255) / 256, 256, 0, stream>>>(
        cnnbf_w, rb1w, rb2w, fc1w, fc2w, rbl1w, rbl2w, mll1w, mll2w, mlf1w, mlf2w, ws);

    mega_kernel<<<B_ * NE_ / 2, 256, 0, stream>>>(
        states, latent, cnnbf_b, rb1b, rb2b, rbl1b, rbl2b, fc1b,
        recv_idx, send_idx, ws, hbar);

    tail_kernel<<<(B_ * NE_) / 64, 256, 0, stream>>>(
        latent, fc2b, mlf1b, mlf2b, mll1b, mll2b, em_w, em_b, ws, hbar, out);
}

// Round 7
// 297.556 us; speedup vs baseline: 11.4773x; 1.1840x over previous
//
#include <hip/hip_runtime.h>

#define B_      2
#define NO_     96
#define T_      50
#define SD_     4
#define NE_     (NO_*(NO_-1))   /* 9120 */
#define F_      64
#define NW_     15

typedef __attribute__((ext_vector_type(8))) short  short8;   /* bf16x8 MFMA frag */
typedef __attribute__((ext_vector_type(4))) float  f32x4;
typedef __attribute__((ext_vector_type(4))) unsigned short u16x4;
typedef __attribute__((ext_vector_type(2))) unsigned int   u32x2;

/* ---- ws layout: bf16 pool (ushort) at byte 8192, element offsets ---- */
#define E_CONVA 0        /* [4 conv][4 m][10 kk][64][8]      = 81920 */
#define E_FC1A  81920    /* [4 m][16 kk][64][8] k=kt*64+f    = 32768 */
#define E_RBL   114688   /* rb cond frags [32 nt][2 kk][64][8]=32768 */
#define E_CONDP 147456   /* [3 mb][16 nt][2 kk][64][8]       = 49152 */
#define E_FCP   196608   /* [7 g][4 nt][2 kk][64][8]         = 28672 */
#define E_C0A   225280   /* conv0 A frags [4 m][64][8]       = 2048  */
#define N_BF16  227328
#define HBAR_F32 115712          /* float offset: (8192 + 2*N_BF16)/4 */

/* frag-index bases (element offset / 8) */
#define FI_FC1   10240
#define FI_RBL   14336
#define FI_CONDP 18432
#define FI_FCP   24576
#define FI_C0A   28160

#define XSTRIDE  3456            /* 54*64 ushorts per edge buffer */

#define MFMA(a, b, c) __builtin_amdgcn_mfma_f32_16x16x32_bf16(a, b, c, 0, 0, 0)

/* fast swish: v * rcp(1+exp(-v)); v_rcp_f32 ~1ulp, fine vs 1.7e-2 threshold */
__device__ __forceinline__ float swish_(float v) {
    return v * __builtin_amdgcn_rcpf(1.f + __expf(-v));
}

__device__ __forceinline__ unsigned short f2bf(float f) {
    unsigned u = __float_as_uint(f);
    u += 0x7FFFu + ((u >> 16) & 1u);
    return (unsigned short)(u >> 16);
}
__device__ __forceinline__ float bf2f(unsigned short u) {
    return __uint_as_float(((unsigned)u) << 16);
}
/* 2×f32 -> packed bf16 pair in one instr (RNE) */
__device__ __forceinline__ unsigned cvtpk(float lo, float hi) {
    unsigned r;
    asm("v_cvt_pk_bf16_f32 %0, %1, %2" : "=v"(r) : "v"(lo), "v"(hi));
    return r;
}

/* ------------------------------------------------------------------ */
__global__ void prep_kernel(const float* __restrict__ cnnbf_w,
                            const float* __restrict__ rb1w, const float* __restrict__ rb2w,
                            const float* __restrict__ fc1w, const float* __restrict__ fc2w,
                            const float* __restrict__ rbl1w, const float* __restrict__ rbl2w,
                            const float* __restrict__ mll1w, const float* __restrict__ mll2w,
                            const float* __restrict__ mlf1w, const float* __restrict__ mlf2w,
                            float* __restrict__ ws) {
    int e = blockIdx.x * blockDim.x + threadIdx.x;
    if (e >= N_BF16) return;
    unsigned short* bfp = (unsigned short*)((char*)ws + 8192);
    float v;
    if (e < E_FC1A) {                               /* conv A frags (k = tap*64+fi) */
        int r = e & 511, fid = e >> 9;
        int lane = r >> 3, j = r & 7;
        int kk = fid % 10, m = (fid / 10) & 3, c = fid / 40;
        int fo = m*16 + (lane & 15);
        int kidx = kk*32 + (lane >> 4)*8 + j;
        int k = kidx >> 6, fi = kidx & 63;
        int i = c >> 1;
        const float* src = (c & 1) ? rb2w : rb1w;
        v = src[((i*64 + fo)*64 + fi)*5 + k];
    } else if (e < E_RBL) {                         /* fc1 A frags, k = kt*64+f */
        int e2 = e - E_FC1A;
        int r = e2 & 511, fid = e2 >> 9;
        int lane = r >> 3, j = r & 7;
        int kk = fid & 15, m = fid >> 4;
        int fo = m*16 + (lane & 15);
        int k = kk*32 + (lane >> 4)*8 + j;
        int krow = (k & 63)*8 + (k >> 6);           /* original index = f*8 + kt */
        v = fc1w[fo*512 + krow];
    } else if (e < E_CONDP) {                       /* rb cond B frags */
        int e3 = e - E_RBL;
        int j = e3 & 7, lane = (e3 >> 3) & 63, fid = e3 >> 9;
        int kk = fid & 1, nt = fid >> 1;            /* nt in [0,32) */
        int rb = nt >> 4, which = (nt >> 3) & 1, ot = nt & 7;
        int o = ot*16 + (lane & 15);
        int k = kk*32 + (lane >> 4)*8 + j;
        const float* src = which ? rbl2w : rbl1w;
        v = src[(rb*128 + o)*64 + k];
    } else if (e < E_FCP) {                         /* mb cond B frags */
        int e4 = e - E_CONDP;
        int r = e4 & 511, fid = e4 >> 9;            /* fid = (mb*16+nt)*2+kk */
        int lane = r >> 3, j = r & 7;
        int kk = fid & 1, nt = (fid >> 1) & 15, mb = fid >> 5;
        int n = nt*16 + (lane & 15);
        int which = n >> 7, o = n & 127;
        int k = kk*32 + (lane >> 4)*8 + j;
        const float* src = which ? mll2w : mll1w;
        v = src[(mb*128 + o)*64 + k];
    } else if (e < E_C0A) {                         /* tail fc B frags */
        int e5 = e - E_FCP;
        int r = e5 & 511, fid = e5 >> 9;            /* fid = (g*4+nt)*2+kk */
        int lane = r >> 3, j = r & 7;
        int kk = fid & 1, nt = (fid >> 1) & 3, g = fid >> 3;
        int o = nt*16 + (lane & 15);
        int k = kk*32 + (lane >> 4)*8 + j;
        if (g == 0) v = fc2w[o*64 + k];
        else {
            int mb = (g - 1) >> 1;
            const float* src = ((g - 1) & 1) ? mlf2w : mlf1w;
            v = src[(mb*64 + o)*64 + k];
        }
    } else {                                        /* conv0 A frags (K=24 pad 32) */
        int e6 = e - E_C0A;
        int j = e6 & 7, lane = (e6 >> 3) & 63, m = e6 >> 9;
        int fo = m*16 + (lane & 15);
        int k = (lane >> 4)*8 + j;
        int tap = k >> 3, fi = k & 7;
        v = (tap < 3) ? cnnbf_w[(fo*8 + fi)*3 + tap] : 0.f;
    }
    bfp[e] = f2bf(v);
}

/* ---------------- conv 64->64 k=5 via MFMA, wave=(mi,ni), 2 edges --
   A-fragments loaded ONCE per wave and reused for both edges.
   ISCONV2: residual accumulate via bf16 LDS RMW (own slot, no conflict). */
template<bool ISCONV2>
__device__ __forceinline__ void convpass2e(const short8* __restrict__ AF, int fb,
        const unsigned short* __restrict__ Bb, unsigned short* __restrict__ Db,
        const float* __restrict__ cb,
        const float* __restrict__ gv0, const float* __restrict__ bv0,
        const float* __restrict__ gv1, const float* __restrict__ bv1,
        const int (&dixs)[2][2], bool skip1,
        int lane, int row0, int g0, int mi, int ni) {
    const int t0a = ni * 32;
    f32x4 acc[2][4];
#pragma unroll
    for (int ed = 0; ed < 2; ++ed)
#pragma unroll
        for (int q = 0; q < 4; ++q) acc[ed][q] = (f32x4){0.f,0.f,0.f,0.f};
#pragma unroll
    for (int kk = 0; kk < 10; ++kk) {
        short8 a0 = AF[fb + ((mi*2 + 0)*10 + kk)*64 + lane];
        short8 a1 = AF[fb + ((mi*2 + 1)*10 + kk)*64 + lane];
        const int c  = ((kk & 1) << 2) + g0;
        const int sa = t0a + row0 + (kk >> 1);
        const int ia = sa*64 + ((c ^ (sa & 7)) << 3);
        int ib;
        if (ni == 0) ib = ia + 1024;
        else { const int sb2 = sa + 2; ib = sb2*64 + ((c ^ (sb2 & 7)) << 3); }
#pragma unroll
        for (int ed = 0; ed < 2; ++ed) {
            const unsigned short* Bs = Bb + ed*XSTRIDE;
            short8 b0 = *(const short8*)&Bs[ia];
            short8 b1 = *(const short8*)&Bs[ib];
            acc[ed][0] = MFMA(a0, b0, acc[ed][0]);
            acc[ed][1] = MFMA(a0, b1, acc[ed][1]);
            acc[ed][2] = MFMA(a1, b0, acc[ed][2]);
            acc[ed][3] = MFMA(a1, b1, acc[ed][3]);
        }
    }
#pragma unroll
    for (int ed = 0; ed < 2; ++ed) {
        const float* gv = ed ? gv1 : gv0;
        const float* bv = ed ? bv1 : bv0;
        unsigned short* Dst = Db + ed*XSTRIDE;
#pragma unroll
        for (int a = 0; a < 2; ++a) {
            const int fo0 = (mi*2 + a)*16 + g0*4;
            const f32x4 cb4 = *(const f32x4*)&cb[fo0];
            const f32x4 g4  = *(const f32x4*)&gv[fo0];
            const f32x4 b4  = *(const f32x4*)&bv[fo0];
            f32x4 gcb;
            gcb[0] = g4[0]*cb4[0] + b4[0]; gcb[1] = g4[1]*cb4[1] + b4[1];
            gcb[2] = g4[2]*cb4[2] + b4[2]; gcb[3] = g4[3]*cb4[3] + b4[3];
#pragma unroll
            for (int n = 0; n < 2; ++n) {
                if (n == 1 && skip1) continue;
                const f32x4 A = acc[ed][a*2 + n];
                float s0 = swish_(g4[0]*A[0] + gcb[0]);
                float s1 = swish_(g4[1]*A[1] + gcb[1]);
                float s2 = swish_(g4[2]*A[2] + gcb[2]);
                float s3 = swish_(g4[3]*A[3] + gcb[3]);
                if (ISCONV2) {                       /* residual RMW, own slot */
                    u16x4 old = *(u16x4*)&Dst[dixs[a][n]];
                    s0 += bf2f(old[0]); s1 += bf2f(old[1]);
                    s2 += bf2f(old[2]); s3 += bf2f(old[3]);
                }
                *(u32x2*)&Dst[dixs[a][n]] = (u32x2){cvtpk(s0, s1), cvtpk(s2, s3)};
            }
        }
    }
}

/* ------------------------------------------------------------------ */
__global__ __launch_bounds__(256, 4) void mega_kernel(
    const float* __restrict__ states, const float* __restrict__ latent,
    const float* __restrict__ cnnbf_b,
    const float* __restrict__ rb_conv1_b, const float* __restrict__ rb_conv2_b,
    const float* __restrict__ rb_lfc1_b, const float* __restrict__ rb_lfc2_b,
    const float* __restrict__ mlp1_fc1_b,
    const int* __restrict__ recv_idx, const int* __restrict__ send_idx,
    const float* __restrict__ ws, float* __restrict__ hbar) {

    const int ge0 = blockIdx.x * 2;                /* two edges per block */
    const int tid  = threadIdx.x;
    const int lane = tid & 63;
    const int wv   = tid >> 6;
    const int row0 = lane & 15, g0 = lane >> 4;
    const int mi = wv & 1, ni = wv >> 1;

    __shared__ __align__(16) unsigned short xTb[2*54*64];  /* bf16 trunk, swizzled */
    __shared__ __align__(16) unsigned short hTb[2*54*64];
    __shared__ __align__(16) unsigned short x0Tb[2*54*8];  /* bf16 input, [row][fi] */
    __shared__ __align__(16) unsigned short lat_bfb[2*64];
    __shared__ __align__(16) float cond_sb[2*512];

    const unsigned short* bfp = (const unsigned short*)((const char*)ws + 8192);
    const short8* AF = (const short8*)bfp;

    /* per-wave output-tile addresses (invariant across all conv passes) */
    int dixs[2][2];
    const bool skip1 = (ni == 1) && (row0 < 14);
#pragma unroll
    for (int a = 0; a < 2; ++a) {
        const int fo0 = (mi*2 + a)*16 + g0*4;
#pragma unroll
        for (int n = 0; n < 2; ++n) {
            const int t = ((n == 0) ? ni*32 : (ni == 0 ? 16 : 34)) + row0;
            const int rw = t + 2;
            dixs[a][n] = rw*64 + ((((fo0 >> 3) ^ (rw & 7))) << 3) + (fo0 & 7);
        }
    }

    /* ---- stage 0: zero pads, gather both edges ---- */
    for (int z = tid; z < 512; z += 256) {
        const int edz = z >> 8, rr = (z >> 6) & 3, cc = z & 63;
        const int row = (rr < 2) ? rr : 50 + rr;
        xTb[edz*XSTRIDE + row*64 + cc] = 0;
        hTb[edz*XSTRIDE + row*64 + cc] = 0;
    }
    if (tid < 8) {
        const int edz = tid >> 2, q = tid & 3;
        const int rz = (q == 0) ? 0 : 50 + q;
        short8 zz = {0,0,0,0,0,0,0,0};
        *(short8*)&x0Tb[edz*432 + rz*8] = zz;
    }
    const int b0_ = ge0 / NE_,       e0_ = ge0 % NE_;
    const int b1_ = (ge0+1) / NE_,   e1_ = (ge0+1) % NE_;
    const int rv0 = recv_idx[e0_], sd0 = send_idx[e0_];
    const int rv1 = recv_idx[e1_], sd1 = send_idx[e1_];
    for (int i = tid; i < 2*8*T_; i += 256) {
        const int ed = i / 400, r = i % 400;
        const int c = r / T_, t = r % T_;
        const int node = (c < 4) ? (ed ? rv1 : rv0) : (ed ? sd1 : sd0);
        const int bsel = ed ? b1_ : b0_;
        const float v = states[((bsel*NO_ + node)*T_ + t)*SD_ + (c & 3)];
        x0Tb[ed*432 + (t + 1)*8 + c] = f2bf(v);
    }
    if (tid < 128) {
        const int edz = tid >> 6, c = tid & 63;
        const int bsel = edz ? b1_ : b0_, esel = edz ? e1_ : e0_;
        lat_bfb[edz*64 + c] = f2bf(latent[(bsel*NE_ + esel)*64 + c]);
    }
    __syncthreads();

    /* ---- stage 1: conv0 via MFMA (A shared) + rb conds (B shared) ---- */
    {
        const int t0a = ni * 32;
        const int sa = t0a + row0 + g0;
        const int sb = (ni == 0) ? (sa + 16) : (sa + 2);
        short8 a0 = AF[FI_C0A + (mi*2 + 0)*64 + lane];
        short8 a1 = AF[FI_C0A + (mi*2 + 1)*64 + lane];
        const f32x4 z4 = {0.f,0.f,0.f,0.f};
#pragma unroll
        for (int ed = 0; ed < 2; ++ed) {
            const unsigned short* xp = x0Tb + ed*432;
            short8 b0 = *(const short8*)&xp[sa * 8];
            short8 b1 = *(const short8*)&xp[sb * 8];
            f32x4 c00 = MFMA(a0, b0, z4), c01 = MFMA(a0, b1, z4);
            f32x4 c10 = MFMA(a1, b0, z4), c11 = MFMA(a1, b1, z4);
            unsigned short* xw = xTb + ed*XSTRIDE;
#pragma unroll
            for (int a = 0; a < 2; ++a) {
                const int fo0 = (mi*2 + a)*16 + g0*4;
                const f32x4 cb4 = *(const f32x4*)&cnnbf_b[fo0];
#pragma unroll
                for (int n = 0; n < 2; ++n) {
                    if (n == 1 && skip1) continue;
                    const f32x4 A = (a == 0) ? ((n == 0) ? c00 : c01)
                                             : ((n == 0) ? c10 : c11);
                    const float s0 = swish_(A[0] + cb4[0]);
                    const float s1 = swish_(A[1] + cb4[1]);
                    const float s2 = swish_(A[2] + cb4[2]);
                    const float s3 = swish_(A[3] + cb4[3]);
                    *(u32x2*)&xw[dixs[a][n]] = (u32x2){cvtpk(s0, s1), cvtpk(s2, s3)};
                }
            }
        }
        /* rb conds: wave = (rb, which); weight B-frags shared across edges */
        short8 la0_0 = *(const short8*)&lat_bfb[g0 * 8];
        short8 la1_0 = *(const short8*)&lat_bfb[32 + g0 * 8];
        short8 la0_1 = *(const short8*)&lat_bfb[64 + g0 * 8];
        short8 la1_1 = *(const short8*)&lat_bfb[96 + g0 * 8];
        const int rbq = wv >> 1, whq = wv & 1;
        const float* cbias = (whq ? rb_lfc2_b : rb_lfc1_b) + rbq*128;
#pragma unroll
        for (int q8 = 0; q8 < 8; ++q8) {
            short8 w0 = AF[FI_RBL + ((wv*8 + q8)*2 + 0)*64 + lane];
            short8 w1 = AF[FI_RBL + ((wv*8 + q8)*2 + 1)*64 + lane];
            f32x4 d0 = MFMA(la1_0, w1, MFMA(la0_0, w0, z4));
            f32x4 d1 = MFMA(la1_1, w1, MFMA(la0_1, w0, z4));
            if (g0 == 0) {
                const int o = q8*16 + row0;
                cond_sb[rbq*256 + whq*128 + o]       = d0[0] + cbias[o];
                cond_sb[512 + rbq*256 + whq*128 + o] = d1[0] + cbias[o];
            }
        }
    }
    __syncthreads();

    /* ---- stage 2: residual blocks (2 edges interleaved) ---- */
#pragma unroll 1
    for (int rb = 0; rb < 2; ++rb) {
        const float* c0 = cond_sb + rb*256;
        const float* c1 = cond_sb + 512 + rb*256;
        convpass2e<false>(AF, (rb*2 + 0)*2560, xTb, hTb, rb_conv1_b + rb*64,
                          c0, c0 + 64, c1, c1 + 64, dixs, skip1,
                          lane, row0, g0, mi, ni);
        __syncthreads();
        convpass2e<true>(AF, (rb*2 + 1)*2560, hTb, xTb, rb_conv2_b + rb*64,
                         c0 + 128, c0 + 192, c1 + 128, c1 + 192, dixs, skip1,
                         lane, row0, g0, mi, ni);
        __syncthreads();
    }

    /* ---- stage 3: windowed MLP fc1 (A shared) + folded mean ---- */
    {
        const int h = g0, nw = row0;
        f32x4 acc3[2];
        acc3[0] = (f32x4){0.f,0.f,0.f,0.f}; acc3[1] = acc3[0];
        const int nwe = (nw < 15) ? nw : 14;
        const int nwrow = 3*nwe + 2;
#pragma unroll
        for (int kk = 0; kk < 16; ++kk) {
            short8 a = AF[FI_FC1 + (wv*16 + kk)*64 + lane];
            const int row = nwrow + (kk >> 1);
            const int g   = ((kk & 1) << 2) + h;
            const int off = row*64 + ((g ^ (row & 7)) << 3);
#pragma unroll
            for (int ed = 0; ed < 2; ++ed) {
                short8 bfr = *(const short8*)&xTb[ed*XSTRIDE + off];
                acc3[ed] = MFMA(a, bfr, acc3[ed]);
            }
        }
        const f32x4 fb = *(const f32x4*)&mlp1_fc1_b[wv*16 + h*4];
#pragma unroll
        for (int ed = 0; ed < 2; ++ed) {
            float red[4];
#pragma unroll
            for (int r = 0; r < 4; ++r) {
                float v = (nw < 15) ? swish_(acc3[ed][r] + fb[r]) : 0.f;
                v += __shfl_xor(v, 1); v += __shfl_xor(v, 2);
                v += __shfl_xor(v, 4); v += __shfl_xor(v, 8);
                red[r] = v * (1.f / 15.f);
            }
            if (nw == 0) {
                f32x4 o4; o4[0] = red[0]; o4[1] = red[1]; o4[2] = red[2]; o4[3] = red[3];
                *(f32x4*)&hbar[(ge0 + ed)*64 + wv*16 + h*4] = o4;
            }
        }
    }
}

/* ---------------- tail: fc2 + 3 cond-MLP blocks + head, 64 edges/block ---- */
__global__ __launch_bounds__(256) void tail_kernel(
    const float* __restrict__ latent,
    const float* __restrict__ fc2b_g,
    const float* __restrict__ mlf1b, const float* __restrict__ mlf2b,
    const float* __restrict__ mll1b, const float* __restrict__ mll2b,
    const float* __restrict__ em_w, const float* __restrict__ em_b,
    const float* __restrict__ ws, const float* __restrict__ hbar,
    float* __restrict__ out) {

    const int m0 = blockIdx.x * 64;
    const int tid = threadIdx.x, lane = tid & 63, wv = tid >> 6;
    const int row15 = lane & 15, hgp = lane >> 4;
    const int o_l = wv*16 + row15;                 /* this lane's output col */

    __shared__ __align__(16) unsigned short Hb[2][64*64];  /* bf16, swizzled */
    __shared__ float V[64][68];                            /* fp32 running vec */
    __shared__ float em_s[64];

    const unsigned short* bfp = (const unsigned short*)((const char*)ws + 8192);
    const short8* AFp = (const short8*)bfp;

    if (tid < 64) em_s[tid] = em_w[tid];

    /* load hbar -> Hb[0] */
    {
        const int e = tid >> 2, q = tid & 3;
        const f32x4* src = (const f32x4*)&hbar[(m0 + e)*64 + q*16];
#pragma unroll
        for (int v4 = 0; v4 < 4; ++v4) {
            f32x4 x = src[v4];
            const int o0 = q*16 + v4*4;
            const int slot = o0 >> 3, half = (o0 >> 2) & 1;
            u16x4 p; p[0]=f2bf(x[0]); p[1]=f2bf(x[1]); p[2]=f2bf(x[2]); p[3]=f2bf(x[3]);
            *(u16x4*)&Hb[0][e*64 + ((slot ^ (e & 7)) << 3) + half*4] = p;
        }
    }
    __syncthreads();

    /* latent A-frags, cached */
    short8 lf[4][2];
#pragma unroll
    for (int m = 0; m < 4; ++m)
#pragma unroll
        for (int kk = 0; kk < 2; ++kk) {
            const float* lp = &latent[(m0 + m*16 + row15)*64 + kk*32 + hgp*8];
            f32x4 a = *(const f32x4*)lp, c = *(const f32x4*)(lp + 4);
            short8 f;
            f[0]=f2bf(a[0]); f[1]=f2bf(a[1]); f[2]=f2bf(a[2]); f[3]=f2bf(a[3]);
            f[4]=f2bf(c[0]); f[5]=f2bf(c[1]); f[6]=f2bf(c[2]); f[7]=f2bf(c[3]);
            lf[m][kk] = f;
        }

#define RD_A(buf, m, kk) \
    (*(const short8*)&Hb[buf][(m*16 + row15)*64 + ((((kk)*4 + hgp) ^ ((m*16 + row15) & 7)) << 3)])
#define RD_FCP(g, kk)  AFp[FI_FCP + (((g)*4 + wv)*2 + (kk))*64 + lane]
#define RD_CND(mb, nt, kk) AFp[FI_CONDP + (((mb)*16 + (nt))*2 + (kk))*64 + lane]

    /* GEMM0: stage3 fc2 */
    f32x4 D[4];
#pragma unroll
    for (int m = 0; m < 4; ++m) D[m] = (f32x4){0.f,0.f,0.f,0.f};
#pragma unroll
    for (int kk = 0; kk < 2; ++kk) {
        short8 bfr = RD_FCP(0, kk);
#pragma unroll
        for (int m = 0; m < 4; ++m) D[m] = MFMA(RD_A(0, m, kk), bfr, D[m]);
    }
    {
        const float bias = fc2b_g[o_l];
#pragma unroll
        for (int m = 0; m < 4; ++m)
#pragma unroll
            for (int r = 0; r < 4; ++r) {
                const int ee = m*16 + hgp*4 + r;
                const float v = D[m][r] + bias;
                V[ee][o_l] = v;
                Hb[1][ee*64 + ((((o_l >> 3) ^ (ee & 7))) << 3) + (o_l & 7)] = f2bf(v);
            }
    }
    __syncthreads();

    /* 3 cond-MLP blocks */
#pragma unroll 1
    for (int mb = 0; mb < 3; ++mb) {
        f32x4 G1[4], B1[4];
#pragma unroll
        for (int m = 0; m < 4; ++m) { G1[m] = (f32x4){0.f,0.f,0.f,0.f}; B1[m] = G1[m]; }
#pragma unroll
        for (int kk = 0; kk < 2; ++kk) {
            short8 bg = RD_CND(mb, wv,     kk);
            short8 bb = RD_CND(mb, wv + 4, kk);
#pragma unroll
            for (int m = 0; m < 4; ++m) {
                G1[m] = MFMA(lf[m][kk], bg, G1[m]);
                B1[m] = MFMA(lf[m][kk], bb, B1[m]);
            }
        }
        f32x4 D1[4];
#pragma unroll
        for (int m = 0; m < 4; ++m) D1[m] = (f32x4){0.f,0.f,0.f,0.f};
#pragma unroll
        for (int kk = 0; kk < 2; ++kk) {
            short8 bfr = RD_FCP(1 + mb*2, kk);
#pragma unroll
            for (int m = 0; m < 4; ++m) D1[m] = MFMA(RD_A(1, m, kk), bfr, D1[m]);
        }
        {
            const float bfc  = mlf1b[mb*64 + o_l];
            const float bg1  = mll1b[mb*128 + o_l];
            const float bb1  = mll1b[mb*128 + 64 + o_l];
#pragma unroll
            for (int m = 0; m < 4; ++m)
#pragma unroll
                for (int r = 0; r < 4; ++r) {
                    const int ee = m*16 + hgp*4 + r;
                    const float h1 = swish_((G1[m][r] + bg1) * (D1[m][r] + bfc)
                                            + (B1[m][r] + bb1));
                    Hb[0][ee*64 + ((((o_l >> 3) ^ (ee & 7))) << 3) + (o_l & 7)] = f2bf(h1);
                }
        }
        __syncthreads();

        f32x4 G2[4], B2[4];
#pragma unroll
        for (int m = 0; m < 4; ++m) { G2[m] = (f32x4){0.f,0.f,0.f,0.f}; B2[m] = G2[m]; }
#pragma unroll
        for (int kk = 0; kk < 2; ++kk) {
            short8 bg = RD_CND(mb, wv + 8,  kk);
            short8 bb = RD_CND(mb, wv + 12, kk);
#pragma unroll
            for (int m = 0; m < 4; ++m) {
                G2[m] = MFMA(lf[m][kk], bg, G2[m]);
                B2[m] = MFMA(lf[m][kk], bb, B2[m]);
            }
        }
        f32x4 D2[4];
#pragma unroll
        for (int m = 0; m < 4; ++m) D2[m] = (f32x4){0.f,0.f,0.f,0.f};
#pragma unroll
        for (int kk = 0; kk < 2; ++kk) {
            short8 bfr = RD_FCP(2 + mb*2, kk);
#pragma unroll
            for (int m = 0; m < 4; ++m) D2[m] = MFMA(RD_A(0, m, kk), bfr, D2[m]);
        }
        {
            const float bfc  = mlf2b[mb*64 + o_l];
            const float bg2  = mll2b[mb*128 + o_l];
            const float bb2  = mll2b[mb*128 + 64 + o_l];
#pragma unroll
            for (int m = 0; m < 4; ++m)
#pragma unroll
                for (int r = 0; r < 4; ++r) {
                    const int ee = m*16 + hgp*4 + r;
                    const float add = swish_((G2[m][r] + bg2) * (D2[m][r] + bfc)
                                             + (B2[m][r] + bb2));
                    const float vn = V[ee][o_l] + add;
                    V[ee][o_l] = vn;
                    Hb[1][ee*64 + ((((o_l >> 3) ^ (ee & 7))) << 3) + (o_l & 7)] = f2bf(vn);
                }
        }
        __syncthreads();
    }

    /* head */
    if (tid < 64) {
        const int ee = tid;
        float acc = em_b[0];
#pragma unroll 16
        for (int j = 0; j < 64; ++j) {
            const int o = (j + ee) & 63;
            acc += V[ee][o] * em_s[o];
        }
        out[m0 + ee] = acc;
    }
}

extern "C" void kernel_launch(void* const* d_in, const int* in_sizes, int n_in,
                              void* d_out, int out_size, void* d_ws, size_t ws_size,
                              hipStream_t stream) {
    const float* states   = (const float*)d_in[0];
    const float* latent   = (const float*)d_in[1];
    const float* cnnbf_w  = (const float*)d_in[2];
    const float* cnnbf_b  = (const float*)d_in[3];
    const float* rb1w     = (const float*)d_in[4];
    const float* rb1b     = (const float*)d_in[5];
    const float* rb2w     = (const float*)d_in[6];
    const float* rb2b     = (const float*)d_in[7];
    const float* rbl1w    = (const float*)d_in[8];
    const float* rbl1b    = (const float*)d_in[9];
    const float* rbl2w    = (const float*)d_in[10];
    const float* rbl2b    = (const float*)d_in[11];
    const float* fc1w     = (const float*)d_in[12];
    const float* fc1b     = (const float*)d_in[13];
    const float* fc2w     = (const float*)d_in[14];
    const float* fc2b     = (const float*)d_in[15];
    const float* mlf1w    = (const float*)d_in[16];
    const float* mlf1b    = (const float*)d_in[17];
    const float* mlf2w    = (const float*)d_in[18];
    const float* mlf2b    = (const float*)d_in[19];
    const float* mll1w    = (const float*)d_in[20];
    const float* mll1b    = (const float*)d_in[21];
    const float* mll2w    = (const float*)d_in[22];
    const float* mll2b    = (const float*)d_in[23];
    const float* em_w     = (const float*)d_in[24];
    const float* em_b     = (const float*)d_in[25];
    const int*   recv_idx = (const int*)d_in[26];
    const int*   send_idx = (const int*)d_in[27];
    float* ws  = (float*)d_ws;
    float* out = (float*)d_out;
    float* hbar = ws + HBAR_F32;

    prep_kernel<<<(N_BF16 + 255) / 256, 256, 0, stream>>>(
        cnnbf_w, rb1w, rb2w, fc1w, fc2w, rbl1w, rbl2w, mll1w, mll2w, mlf1w, mlf2w, ws);

    mega_kernel<<<B_ * NE_ / 2, 256, 0, stream>>>(
        states, latent, cnnbf_b, rb1b, rb2b, rbl1b, rbl2b, fc1b,
        recv_idx, send_idx, ws, hbar);

    tail_kernel<<<(B_ * NE_) / 64, 256, 0, stream>>>(
        latent, fc2b, mlf1b, mlf2b, mll1b, mll2b, em_w, em_b, ws, hbar, out);
}